// Round 4
// baseline (8318.213 us; speedup 1.0000x reference)
//
#include <hip/hip_runtime.h>
#include <hip/hip_bf16.h>

#define BB 2
#define TT 2048
#define DD 1024
#define NH 16
#define HDIM 64
#define HALF 1024
#define DHID 4096
#define ND9 9216
#define ROWS (BB*TT)

using bf16 = __hip_bfloat16;

__device__ __forceinline__ float b2f(bf16 v){ return __bfloat162float(v); }
__device__ __forceinline__ bf16 f2b(float v){ return __float2bfloat16(v); }

// ---------------- mod = silu(c) @ ada_w + ada_b  (4 rows x 9216) ----------------
__global__ void ada_kernel(const float* __restrict__ c, const float* __restrict__ ada_w,
                           const float* __restrict__ ada_b, float* __restrict__ mod) {
    __shared__ float sc_[DD];
    int r = blockIdx.y;                       // 0..3  (b*2+cz)
    int n = blockIdx.x * 256 + threadIdx.x;   // 0..9215
    for (int k = threadIdx.x; k < DD; k += 256) {
        float v = c[r*DD + k];
        sc_[k] = v / (1.f + __expf(-v));
    }
    __syncthreads();
    float acc = 0.f;
    for (int k = 0; k < DD; ++k) acc += sc_[k] * ada_w[(size_t)k*ND9 + n];
    mod[r*ND9 + n] = acc + ada_b[n];
}

// ---------------- resid(out) = copy(x) ----------------
__global__ void cast_x(const float* __restrict__ x, float* __restrict__ xc, int n) {
    int i = blockIdx.x * 256 + threadIdx.x;
    if (i < n) xc[i] = x[i];
}

// ---------------- y = mod(ln(src), shift, scale) as bf16 ----------------
__global__ void ln_mod_kernel(const float* __restrict__ xc, const float* __restrict__ mod,
                              int jshift, int jscale, bf16* __restrict__ y) {
    int row = blockIdx.x;                 // 0..4095
    int b = row / TT, t = row % TT;
    int cz = (t >= HALF) ? 1 : 0;
    const float* mp = mod + (size_t)(b*2 + cz) * ND9;
    const float* xr = xc + (size_t)row * DD;
    int tid = threadIdx.x;
    float v[4];
    float s = 0.f, ss = 0.f;
    #pragma unroll
    for (int i = 0; i < 4; ++i) {
        v[i] = xr[tid + i*256];
        s += v[i]; ss += v[i]*v[i];
    }
    __shared__ float red[256];
    red[tid] = s; __syncthreads();
    for (int o = 128; o > 0; o >>= 1) { if (tid < o) red[tid] += red[tid+o]; __syncthreads(); }
    float mean = red[0] * (1.f/DD);
    __syncthreads();
    red[tid] = ss; __syncthreads();
    for (int o = 128; o > 0; o >>= 1) { if (tid < o) red[tid] += red[tid+o]; __syncthreads(); }
    float var = red[0] * (1.f/DD) - mean*mean;
    float rstd = rsqrtf(var + 1e-6f);
    bf16* yr = y + (size_t)row * DD;
    #pragma unroll
    for (int i = 0; i < 4; ++i) {
        int d = tid + i*256;
        float sh = mp[jshift*DD + d], sc2 = mp[jscale*DD + d];
        yr[d] = f2b((v[i] - mean) * rstd * (1.f + sc2) + sh);
    }
}

// ---------------- generic tiled GEMM with row offsets ----------------
// global row m = m_base + blockIdx.y*64 + (local)
// A row index: m - a_off; out row index: m - o_off
// epi 0: out = bf16(v)
// epi 1: out = bf16(gelu_tanh(v))
// epi 2: resid_out[m*N+n] = resid_in[m*N+n] + mod_g * v    (N == DD)
__global__ void gemm_kernel(const bf16* __restrict__ A, const float* __restrict__ W,
                            const float* __restrict__ bias,
                            bf16* __restrict__ out,
                            const float* __restrict__ resid_in, float* __restrict__ resid_out,
                            const float* __restrict__ mod, int jg,
                            int m_base, int a_off, int o_off,
                            int K, int N, int epi) {
    __shared__ float As[16][68];
    __shared__ float Bs[16][68];
    int m0 = m_base + blockIdx.y * 64, n0 = blockIdx.x * 64;
    int tid = threadIdx.x;
    int tx = tid & 15, ty = tid >> 4;
    float acc[4][4] = {};
    for (int k0 = 0; k0 < K; k0 += 16) {
        #pragma unroll
        for (int i = 0; i < 4; ++i) {
            int idx = tid + i*256;
            int m = idx >> 4, k = idx & 15;
            As[k][m] = b2f(A[(size_t)(m0 + m - a_off)*K + k0 + k]);
        }
        #pragma unroll
        for (int i = 0; i < 4; ++i) {
            int idx = tid + i*256;
            int k = idx >> 6, n = idx & 63;
            Bs[k][n] = W[(size_t)(k0+k)*N + n0 + n];
        }
        __syncthreads();
        #pragma unroll
        for (int k = 0; k < 16; ++k) {
            float a[4], bb[4];
            #pragma unroll
            for (int i = 0; i < 4; ++i) a[i] = As[k][ty*4+i];
            #pragma unroll
            for (int j = 0; j < 4; ++j) bb[j] = Bs[k][tx*4+j];
            #pragma unroll
            for (int i = 0; i < 4; ++i)
                #pragma unroll
                for (int j = 0; j < 4; ++j)
                    acc[i][j] += a[i]*bb[j];
        }
        __syncthreads();
    }
    #pragma unroll
    for (int i = 0; i < 4; ++i) {
        int m = m0 + ty*4 + i;
        int brow = m / TT, tt = m % TT;
        int cz = (tt >= HALF) ? 1 : 0;
        const float* mp = (epi == 2) ? (mod + (size_t)(brow*2+cz)*ND9 + (size_t)jg*DD) : nullptr;
        #pragma unroll
        for (int j = 0; j < 4; ++j) {
            int n = n0 + tx*4 + j;
            float v = acc[i][j] + bias[n];
            if (epi == 0) {
                out[(size_t)(m - o_off) * N + n] = f2b(v);
            } else if (epi == 1) {
                float u = v;
                float g = 0.5f*u*(1.f + tanhf(0.7978845608028654f*(u + 0.044715f*u*u*u)));
                out[(size_t)(m - o_off) * N + n] = f2b(g);
            } else {
                size_t idx = (size_t)m * N + n;
                resid_out[idx] = resid_in[idx] + mp[n] * v;
            }
        }
    }
}

// ---------------- attention on one batch's qkv chunk ----------------
// qkv: local rows 0..2047 for batch b, row stride 3*DD (bf16)
// grid (HALF/4, NH, 2=hf); block 256 = 4 waves; wave w handles one q-row
__global__ void attn_kernel(const bf16* __restrict__ qkv, bf16* __restrict__ attn_out,
                            int kv_swap, int b) {
    __shared__ float KT[64][65];   // [dim][key]
    __shared__ float Vt[64][65];   // [key][dim]
    __shared__ float qs[4][64];
    int hf = blockIdx.z;
    int head = blockIdx.y;
    int tid = threadIdx.x;
    int w = tid >> 6;
    int lane = tid & 63;
    int qrow_l = hf*HALF + blockIdx.x*4 + w;          // local row in chunk
    int kvhf = kv_swap ? (1 - hf) : hf;
    int kvrow_l = kvhf*HALF;

    qs[w][lane] = b2f(qkv[(size_t)qrow_l*3*DD + head*HDIM + lane]);

    float m = -1e30f, l = 0.f, o = 0.f;

    for (int kt = 0; kt < HALF/64; ++kt) {
        __syncthreads();
        #pragma unroll
        for (int i = 0; i < 16; ++i) {
            int idx = tid + i*256;
            int j = idx >> 6, d = idx & 63;
            size_t row = (size_t)(kvrow_l + kt*64 + j) * (3*DD);
            KT[d][j] = b2f(qkv[row + DD  + head*HDIM + d]);
            Vt[j][d] = b2f(qkv[row + 2*DD + head*HDIM + d]);
        }
        __syncthreads();
        // phase A: lane = key index
        float s = 0.f;
        #pragma unroll
        for (int d2 = 0; d2 < 64; ++d2)
            s += qs[w][d2] * KT[d2][lane];
        s *= 0.125f;
        float tm = s;
        #pragma unroll
        for (int off = 32; off > 0; off >>= 1) tm = fmaxf(tm, __shfl_xor(tm, off));
        float mnew = fmaxf(m, tm);
        float alpha = __expf(m - mnew);
        float p = __expf(s - mnew);
        float ts = p;
        #pragma unroll
        for (int off = 32; off > 0; off >>= 1) ts += __shfl_xor(ts, off);
        l = l*alpha + ts;
        m = mnew;
        // phase B: lane = dim
        float onew = o * alpha;
        #pragma unroll
        for (int j2 = 0; j2 < 64; ++j2) {
            float pj = __shfl(p, j2);
            onew += pj * Vt[j2][lane];
        }
        o = onew;
    }
    attn_out[(size_t)(b*TT + qrow_l)*DD + head*HDIM + lane] = f2b(o / l);
}

extern "C" void kernel_launch(void* const* d_in, const int* in_sizes, int n_in,
                              void* d_out, int out_size, void* d_ws, size_t ws_size,
                              hipStream_t stream) {
    const float* x          = (const float*)d_in[0];
    const float* c          = (const float*)d_in[1];
    const float* attn_qkv_w = (const float*)d_in[2];
    const float* attn_qkv_b = (const float*)d_in[3];
    const float* attn_proj_w= (const float*)d_in[4];
    const float* attn_proj_b= (const float*)d_in[5];
    const float* crs_qkv_w  = (const float*)d_in[6];
    const float* crs_qkv_b  = (const float*)d_in[7];
    const float* crs_proj_w = (const float*)d_in[8];
    const float* crs_proj_b = (const float*)d_in[9];
    const float* fc1_w      = (const float*)d_in[10];
    const float* fc1_b      = (const float*)d_in[11];
    const float* fc2_w      = (const float*)d_in[12];
    const float* fc2_b      = (const float*)d_in[13];
    const float* ada_w      = (const float*)d_in[14];
    const float* ada_b      = (const float*)d_in[15];
    float* out = (float*)d_out;    // running residual (starts as x; MSA branch NOT accumulated here)

    char* ws = (char*)d_ws;
    float* mod    = (float*)(ws);                          // 147456 B (pad to 256KB)
    float* x0x1   = (float*)(ws + (256u<<10));             // 16 MB: x0/x1 = x + g_msa*msa (feeds MCA ln only)
    bf16*  y      = (bf16*) (ws + (256u<<10) + (16u<<20)); // 8 MB
    bf16*  attn_o = (bf16*) (ws + (256u<<10) + (24u<<20)); // 8 MB
    bf16*  big    = (bf16*) (ws + (256u<<10) + (32u<<20)); // 12 MB chunk staging
    // total ws usage: 44.25 MB

    ada_kernel<<<dim3(ND9/256, 4), 256, 0, stream>>>(c, ada_w, ada_b, mod);
    cast_x<<<(ROWS*DD)/256, 256, 0, stream>>>(x, out, ROWS*DD);

    // ---- self-attention (result goes ONLY into x0x1, not the residual stream) ----
    ln_mod_kernel<<<ROWS, 256, 0, stream>>>(out, mod, 0, 1, y);
    for (int b = 0; b < BB; ++b) {
        gemm_kernel<<<dim3(3*DD/64, TT/64), 256, 0, stream>>>(y, attn_qkv_w, attn_qkv_b, big,
                                                              nullptr, nullptr, nullptr, 0,
                                                              b*TT, 0, b*TT, DD, 3*DD, 0);
        attn_kernel<<<dim3(HALF/4, NH, 2), 256, 0, stream>>>(big, attn_o, 0, b);
    }
    // x0x1 = out(orig x) + g_msa * proj(attn_o)
    gemm_kernel<<<dim3(DD/64, ROWS/64), 256, 0, stream>>>(attn_o, attn_proj_w, attn_proj_b, nullptr,
                                                          out, x0x1, mod, 2,
                                                          0, 0, 0, DD, DD, 2);

    // ---- cross-attention (input ln(x0x1); residual add into out) ----
    ln_mod_kernel<<<ROWS, 256, 0, stream>>>(x0x1, mod, 3, 4, y);
    for (int b = 0; b < BB; ++b) {
        gemm_kernel<<<dim3(3*DD/64, TT/64), 256, 0, stream>>>(y, crs_qkv_w, crs_qkv_b, big,
                                                              nullptr, nullptr, nullptr, 0,
                                                              b*TT, 0, b*TT, DD, 3*DD, 0);
        attn_kernel<<<dim3(HALF/4, NH, 2), 256, 0, stream>>>(big, attn_o, 1, b);
    }
    gemm_kernel<<<dim3(DD/64, ROWS/64), 256, 0, stream>>>(attn_o, crs_proj_w, crs_proj_b, nullptr,
                                                          out, out, mod, 5,
                                                          0, 0, 0, DD, DD, 2);

    // ---- MLP (4 chunks of 1024 rows) ----
    ln_mod_kernel<<<ROWS, 256, 0, stream>>>(out, mod, 6, 7, y);
    for (int ch = 0; ch < 4; ++ch) {
        int r0 = ch * 1024;
        gemm_kernel<<<dim3(DHID/64, 1024/64), 256, 0, stream>>>(y, fc1_w, fc1_b, big,
                                                                nullptr, nullptr, nullptr, 0,
                                                                r0, 0, r0, DD, DHID, 1);
        gemm_kernel<<<dim3(DD/64, 1024/64), 256, 0, stream>>>(big, fc2_w, fc2_b, nullptr,
                                                              out, out, mod, 8,
                                                              r0, r0, 0, DHID, DD, 2);
    }
}

// Round 6
// 1108.322 us; speedup vs baseline: 7.5052x; 7.5052x over previous
//
#include <hip/hip_runtime.h>
#include <hip/hip_bf16.h>

#define BB 2
#define TT 2048
#define DD 1024
#define NH 16
#define HALF 1024
#define DHID 4096
#define ND9 9216
#define ROWS (BB*TT)

using bf16 = __hip_bfloat16;
typedef short bf16x8 __attribute__((ext_vector_type(8)));
typedef float f32x4 __attribute__((ext_vector_type(4)));
typedef unsigned short u16;

__device__ __forceinline__ float b2f(bf16 v){ return __bfloat162float(v); }
__device__ __forceinline__ bf16 f2b(float v){ return __float2bfloat16(v); }
__device__ __forceinline__ u16 fb(float v){              // float -> bf16 bits (RNE)
    unsigned u = __float_as_uint(v);
    u += 0x7fffu + ((u >> 16) & 1u);
    return (u16)(u >> 16);
}

// ---------------- mod = silu(c) @ ada_w + ada_b  (4 rows x 9216) ----------------
__global__ void ada_kernel(const float* __restrict__ c, const float* __restrict__ ada_w,
                           const float* __restrict__ ada_b, float* __restrict__ mod) {
    __shared__ float sc_[DD];
    int r = blockIdx.y;
    int n = blockIdx.x * 256 + threadIdx.x;
    for (int k = threadIdx.x; k < DD; k += 256) {
        float v = c[r*DD + k];
        sc_[k] = v / (1.f + __expf(-v));
    }
    __syncthreads();
    float acc = 0.f;
    for (int k = 0; k < DD; ++k) acc += sc_[k] * ada_w[(size_t)k*ND9 + n];
    mod[r*ND9 + n] = acc + ada_b[n];
}

// ---------------- resid(out) = copy(x) ----------------
__global__ void cast_x(const float* __restrict__ x, float* __restrict__ xc, int n) {
    int i = blockIdx.x * 256 + threadIdx.x;
    if (i < n) xc[i] = x[i];
}

// ---------------- W (KxN f32) -> Wt (NxK bf16 bits) ----------------
__global__ void transpose_w(const float* __restrict__ W, u16* __restrict__ Wt, int K, int N) {
    __shared__ float T[32][33];
    int n0 = blockIdx.x * 32, k0 = blockIdx.y * 32;
    int lx = threadIdx.x & 31, ly = threadIdx.x >> 5;   // 256 thr = 32 x 8
    #pragma unroll
    for (int i = 0; i < 4; ++i)
        T[ly + i*8][lx] = W[(size_t)(k0 + ly + i*8)*N + n0 + lx];
    __syncthreads();
    #pragma unroll
    for (int i = 0; i < 4; ++i) {
        int n = ly + i*8;
        Wt[(size_t)(n0 + n)*K + k0 + lx] = fb(T[lx][n]);
    }
}

// ---------------- y = mod(ln(src), shift, scale) as bf16 ----------------
__global__ void ln_mod_kernel(const float* __restrict__ xc, const float* __restrict__ mod,
                              int jshift, int jscale, bf16* __restrict__ y) {
    int row = blockIdx.x;
    int b = row / TT, t = row % TT;
    int cz = (t >= HALF) ? 1 : 0;
    const float* mp = mod + (size_t)(b*2 + cz) * ND9;
    const float* xr = xc + (size_t)row * DD;
    int tid = threadIdx.x;
    float v[4];
    float s = 0.f, ss = 0.f;
    #pragma unroll
    for (int i = 0; i < 4; ++i) {
        v[i] = xr[tid + i*256];
        s += v[i]; ss += v[i]*v[i];
    }
    __shared__ float red[256];
    red[tid] = s; __syncthreads();
    for (int o = 128; o > 0; o >>= 1) { if (tid < o) red[tid] += red[tid+o]; __syncthreads(); }
    float mean = red[0] * (1.f/DD);
    __syncthreads();
    red[tid] = ss; __syncthreads();
    for (int o = 128; o > 0; o >>= 1) { if (tid < o) red[tid] += red[tid+o]; __syncthreads(); }
    float var = red[0] * (1.f/DD) - mean*mean;
    float rstd = rsqrtf(var + 1e-6f);
    bf16* yr = y + (size_t)row * DD;
    #pragma unroll
    for (int i = 0; i < 4; ++i) {
        int d = tid + i*256;
        float sh = mp[jshift*DD + d], sc2 = mp[jscale*DD + d];
        yr[d] = f2b((v[i] - mean) * rstd * (1.f + sc2) + sh);
    }
}

// ---------------- MFMA GEMM: C = A(MxK bf16) @ Wt^T(NxK bf16) + bias ----------------
// 64x64 tile/block, 4 waves, wave w -> rows w*16..+16, BK=32
// epi 0: out = bf16(v); epi 1: out = bf16(gelu_tanh(v));
// epi 2: resid_out[m*N+n] = resid_in[m*N+n] + mod_g*v  (N == DD)
__global__ void gemm_mfma(const u16* __restrict__ A, const u16* __restrict__ Wt,
                          const float* __restrict__ bias,
                          u16* __restrict__ out,
                          const float* __restrict__ resid_in, float* __restrict__ resid_out,
                          const float* __restrict__ mod, int jg,
                          int m_base, int a_off, int o_off,
                          int K, int N, int epi) {
    __shared__ u16 As[64][40];
    __shared__ u16 Bs[64][40];
    int m0 = m_base + blockIdx.y * 64;
    int n0 = blockIdx.x * 64;
    int tid = threadIdx.x;
    int w = tid >> 6, lane = tid & 63;
    int quad = lane >> 4, l16 = lane & 15;
    f32x4 acc[4];
    #pragma unroll
    for (int i = 0; i < 4; ++i) acc[i] = (f32x4){0.f, 0.f, 0.f, 0.f};

    int sm = tid >> 2, skc = (tid & 3) * 8;
    for (int k0 = 0; k0 < K; k0 += 32) {
        __syncthreads();
        *(uint4*)&As[sm][skc] = *(const uint4*)(A  + (size_t)(m0 + sm - a_off)*K + k0 + skc);
        *(uint4*)&Bs[sm][skc] = *(const uint4*)(Wt + (size_t)(n0 + sm)*K        + k0 + skc);
        __syncthreads();
        bf16x8 af = *(const bf16x8*)&As[w*16 + l16][quad*8];
        #pragma unroll
        for (int nt = 0; nt < 4; ++nt) {
            bf16x8 bfv = *(const bf16x8*)&Bs[nt*16 + l16][quad*8];
            acc[nt] = __builtin_amdgcn_mfma_f32_16x16x32_bf16(af, bfv, acc[nt], 0, 0, 0);
        }
    }
    #pragma unroll
    for (int nt = 0; nt < 4; ++nt) {
        #pragma unroll
        for (int r = 0; r < 4; ++r) {
            int m = m0 + w*16 + quad*4 + r;
            int n = n0 + nt*16 + l16;
            float v = acc[nt][r] + bias[n];
            if (epi == 0) {
                out[(size_t)(m - o_off)*N + n] = fb(v);
            } else if (epi == 1) {
                float u = v;
                float g = 0.5f*u*(1.f + tanhf(0.7978845608028654f*(u + 0.044715f*u*u*u)));
                out[(size_t)(m - o_off)*N + n] = fb(g);
            } else {
                int brow = m / TT, tt2 = m % TT;
                int cz = (tt2 >= HALF) ? 1 : 0;
                const float* mp = mod + (size_t)(brow*2 + cz)*ND9 + (size_t)jg*DD;
                size_t idx = (size_t)m*N + n;
                resid_out[idx] = resid_in[idx] + mp[n]*v;
            }
        }
    }
}

// ---------------- MFMA flash attention on one batch's qkv chunk ----------------
// qkv: local rows 0..2047 (bf16 bits), row stride 3*DD; q|k|v at col 0|DD|2DD (+head*64)
// grid (16 qtiles, NH, 2 hf); block 256 = 4 waves; wave w handles 16 q-rows
__global__ void attn_mfma(const u16* __restrict__ qkv, u16* __restrict__ attn_out,
                          int kv_swap, int b) {
    __shared__ u16 Ks[64][72];       // [key][d]
    __shared__ u16 Vt[64][72];       // [d][key]
    __shared__ u16 Ps[4][16][72];    // per-wave P: [qrow][key]
    int qt = blockIdx.x, head = blockIdx.y, hf = blockIdx.z;
    int tid = threadIdx.x;
    int w = tid >> 6, lane = tid & 63;
    int quad = lane >> 4, l16 = lane & 15;
    int kvhf = kv_swap ? (1 - hf) : hf;
    int qrow0 = hf*HALF + qt*64 + w*16;     // local row
    int kvbase = kvhf*HALF;

    const u16* qp = qkv + (size_t)(qrow0 + l16)*(3*DD) + head*64;
    bf16x8 qa0 = *(const bf16x8*)(qp + quad*8);
    bf16x8 qa1 = *(const bf16x8*)(qp + 32 + quad*8);

    f32x4 oacc[4];
    #pragma unroll
    for (int i = 0; i < 4; ++i) oacc[i] = (f32x4){0.f, 0.f, 0.f, 0.f};
    float mst[4], lst[4];
    #pragma unroll
    for (int r = 0; r < 4; ++r) { mst[r] = -3e38f; lst[r] = 0.f; }

    for (int kt = 0; kt < HALF/64; ++kt) {
        __syncthreads();
        #pragma unroll
        for (int i = 0; i < 2; ++i) {
            int idx = tid + i*256;
            int key = idx >> 3, cc = idx & 7;
            *(uint4*)&Ks[key][cc*8] =
                *(const uint4*)(qkv + (size_t)(kvbase + kt*64 + key)*(3*DD) + DD + head*64 + cc*8);
        }
        #pragma unroll
        for (int i = 0; i < 8; ++i) {
            int idx = tid + i*256;
            int key = idx >> 5, d = (idx & 31)*2;
            unsigned v2 = *(const unsigned*)(qkv + (size_t)(kvbase + kt*64 + key)*(3*DD) + 2*DD + head*64 + d);
            Vt[d][key]     = (u16)(v2 & 0xffffu);
            Vt[d + 1][key] = (u16)(v2 >> 16);
        }
        __syncthreads();

        // S = Q K^T for this 64-key tile
        f32x4 sacc[4];
        #pragma unroll
        for (int nt = 0; nt < 4; ++nt) sacc[nt] = (f32x4){0.f, 0.f, 0.f, 0.f};
        #pragma unroll
        for (int nt = 0; nt < 4; ++nt) {
            bf16x8 kb0 = *(const bf16x8*)&Ks[nt*16 + l16][quad*8];
            bf16x8 kb1 = *(const bf16x8*)&Ks[nt*16 + l16][32 + quad*8];
            sacc[nt] = __builtin_amdgcn_mfma_f32_16x16x32_bf16(qa0, kb0, sacc[nt], 0, 0, 0);
            sacc[nt] = __builtin_amdgcn_mfma_f32_16x16x32_bf16(qa1, kb1, sacc[nt], 0, 0, 0);
        }
        // online softmax; lane holds rows quad*4+r, key nt*16+l16
        #pragma unroll
        for (int r = 0; r < 4; ++r) {
            float sv0 = sacc[0][r]*0.125f, sv1 = sacc[1][r]*0.125f;
            float sv2 = sacc[2][r]*0.125f, sv3 = sacc[3][r]*0.125f;
            float mx = fmaxf(fmaxf(sv0, sv1), fmaxf(sv2, sv3));
            #pragma unroll
            for (int o = 1; o < 16; o <<= 1) mx = fmaxf(mx, __shfl_xor(mx, o));
            float mnew = fmaxf(mst[r], mx);
            float alpha = __expf(mst[r] - mnew);
            float p0 = __expf(sv0 - mnew), p1 = __expf(sv1 - mnew);
            float p2 = __expf(sv2 - mnew), p3 = __expf(sv3 - mnew);
            float ls = p0 + p1 + p2 + p3;
            #pragma unroll
            for (int o = 1; o < 16; o <<= 1) ls += __shfl_xor(ls, o);
            lst[r] = lst[r]*alpha + ls;
            mst[r] = mnew;
            #pragma unroll
            for (int dt = 0; dt < 4; ++dt) oacc[dt][r] *= alpha;
            int qr = quad*4 + r;
            Ps[w][qr][ 0 + l16] = fb(p0);
            Ps[w][qr][16 + l16] = fb(p1);
            Ps[w][qr][32 + l16] = fb(p2);
            Ps[w][qr][48 + l16] = fb(p3);
        }
        // O += P V
        bf16x8 pa0 = *(const bf16x8*)&Ps[w][l16][quad*8];
        bf16x8 pa1 = *(const bf16x8*)&Ps[w][l16][32 + quad*8];
        #pragma unroll
        for (int dt = 0; dt < 4; ++dt) {
            bf16x8 vb0 = *(const bf16x8*)&Vt[dt*16 + l16][quad*8];
            bf16x8 vb1 = *(const bf16x8*)&Vt[dt*16 + l16][32 + quad*8];
            oacc[dt] = __builtin_amdgcn_mfma_f32_16x16x32_bf16(pa0, vb0, oacc[dt], 0, 0, 0);
            oacc[dt] = __builtin_amdgcn_mfma_f32_16x16x32_bf16(pa1, vb1, oacc[dt], 0, 0, 0);
        }
    }
    #pragma unroll
    for (int dt = 0; dt < 4; ++dt)
        #pragma unroll
        for (int r = 0; r < 4; ++r) {
            int qrow = qrow0 + quad*4 + r;
            attn_out[(size_t)(b*TT + qrow)*DD + head*64 + dt*16 + l16] = fb(oacc[dt][r] / lst[r]);
        }
}

extern "C" void kernel_launch(void* const* d_in, const int* in_sizes, int n_in,
                              void* d_out, int out_size, void* d_ws, size_t ws_size,
                              hipStream_t stream) {
    const float* x          = (const float*)d_in[0];
    const float* c          = (const float*)d_in[1];
    const float* attn_qkv_w = (const float*)d_in[2];
    const float* attn_qkv_b = (const float*)d_in[3];
    const float* attn_proj_w= (const float*)d_in[4];
    const float* attn_proj_b= (const float*)d_in[5];
    const float* crs_qkv_w  = (const float*)d_in[6];
    const float* crs_qkv_b  = (const float*)d_in[7];
    const float* crs_proj_w = (const float*)d_in[8];
    const float* crs_proj_b = (const float*)d_in[9];
    const float* fc1_w      = (const float*)d_in[10];
    const float* fc1_b      = (const float*)d_in[11];
    const float* fc2_w      = (const float*)d_in[12];
    const float* fc2_b      = (const float*)d_in[13];
    const float* ada_w      = (const float*)d_in[14];
    const float* ada_b      = (const float*)d_in[15];
    float* out = (float*)d_out;     // f32 running residual (= x; MSA branch excluded per reference)

    // ws regions (total 44.25 MB, time-multiplexed; liveness verified dispatch-by-dispatch)
    char* ws = (char*)d_ws;
    float* mod    = (float*)ws;                                // 0.25 MB
    char*  R1     = ws + (256u<<10);                           // 16 MB
    char*  Yr     = ws + (256u<<10) + (16u<<20);               // 8 MB
    char*  AOr    = ws + (256u<<10) + (24u<<20);               // 8 MB
    char*  BIGr   = ws + (256u<<10) + (32u<<20);               // 12 MB

    float* x0x1   = (float*)R1;          // live: MSA-proj -> MCA-ln
    bf16*  y      = (bf16*)Yr;           // ln output
    u16*   attn_o = (u16*)AOr;
    u16*   big    = (u16*)BIGr;          // per-batch qkv (12 MB)
    u16* msa_qkv_t = (u16*)R1;           // 6 MB  (dead before x0x1 written)
    u16* msa_proj_t= (u16*)Yr;           // 2 MB  (after y consumed)
    u16* mca_qkv_t = (u16*)R1;           // 6 MB  (AFTER MCA ln consumes x0x1 — fixes AOr clash)
    u16* mca_proj_t= (u16*)Yr;           // 2 MB  (after y consumed)
    u16* fc1_t     = (u16*)R1;           // 8 MB
    u16* fc2_t     = (u16*)(R1 + (8u<<20)); // 8 MB
    u16* hstage    = (u16*)BIGr;         // 8 MB  (after big dead)

    ada_kernel<<<dim3(ND9/256, 4), 256, 0, stream>>>(c, ada_w, ada_b, mod);
    cast_x<<<(ROWS*DD)/256, 256, 0, stream>>>(x, out, ROWS*DD);

    // ================= MSA =================
    transpose_w<<<dim3(3*DD/32, DD/32), 256, 0, stream>>>(attn_qkv_w, msa_qkv_t, DD, 3*DD);
    ln_mod_kernel<<<ROWS, 256, 0, stream>>>(out, mod, 0, 1, y);
    for (int b = 0; b < BB; ++b) {
        gemm_mfma<<<dim3(3*DD/64, TT/64), 256, 0, stream>>>((const u16*)y, msa_qkv_t, attn_qkv_b,
                                                            big, nullptr, nullptr, nullptr, 0,
                                                            b*TT, 0, b*TT, DD, 3*DD, 0);
        attn_mfma<<<dim3(16, NH, 2), 256, 0, stream>>>(big, attn_o, 0, b);
    }
    transpose_w<<<dim3(DD/32, DD/32), 256, 0, stream>>>(attn_proj_w, msa_proj_t, DD, DD);
    // x0x1 = out + g_msa * proj(attn_o)
    gemm_mfma<<<dim3(DD/64, ROWS/64), 256, 0, stream>>>(attn_o, msa_proj_t, attn_proj_b,
                                                        nullptr, out, x0x1, mod, 2,
                                                        0, 0, 0, DD, DD, 2);

    // ================= MCA =================
    // ln FIRST (consumes x0x1 in R1), THEN transpose qkv weights into R1.
    ln_mod_kernel<<<ROWS, 256, 0, stream>>>(x0x1, mod, 3, 4, y);
    transpose_w<<<dim3(3*DD/32, DD/32), 256, 0, stream>>>(crs_qkv_w, mca_qkv_t, DD, 3*DD);
    for (int b = 0; b < BB; ++b) {
        gemm_mfma<<<dim3(3*DD/64, TT/64), 256, 0, stream>>>((const u16*)y, mca_qkv_t, crs_qkv_b,
                                                            big, nullptr, nullptr, nullptr, 0,
                                                            b*TT, 0, b*TT, DD, 3*DD, 0);
        attn_mfma<<<dim3(16, NH, 2), 256, 0, stream>>>(big, attn_o, 1, b);
    }
    transpose_w<<<dim3(DD/32, DD/32), 256, 0, stream>>>(crs_proj_w, mca_proj_t, DD, DD);
    gemm_mfma<<<dim3(DD/64, ROWS/64), 256, 0, stream>>>(attn_o, mca_proj_t, crs_proj_b,
                                                        nullptr, out, out, mod, 5,
                                                        0, 0, 0, DD, DD, 2);

    // ================= MLP =================
    ln_mod_kernel<<<ROWS, 256, 0, stream>>>(out, mod, 6, 7, y);
    transpose_w<<<dim3(DHID/32, DD/32), 256, 0, stream>>>(fc1_w, fc1_t, DD, DHID);
    transpose_w<<<dim3(DD/32, DHID/32), 256, 0, stream>>>(fc2_w, fc2_t, DHID, DD);
    for (int ch = 0; ch < 4; ++ch) {
        int r0 = ch * 1024;
        gemm_mfma<<<dim3(DHID/64, 1024/64), 256, 0, stream>>>((const u16*)y, fc1_t, fc1_b,
                                                              hstage, nullptr, nullptr, nullptr, 0,
                                                              r0, 0, r0, DD, DHID, 1);
        gemm_mfma<<<dim3(DD/64, 1024/64), 256, 0, stream>>>(hstage, fc2_t, fc2_b,
                                                            nullptr, out, out, mod, 8,
                                                            r0, r0, 0, DHID, DD, 2);
    }
}

// Round 7
// 1089.998 us; speedup vs baseline: 7.6314x; 1.0168x over previous
//
#include <hip/hip_runtime.h>
#include <hip/hip_bf16.h>

#define BB 2
#define TT 2048
#define DD 1024
#define NH 16
#define HALF 1024
#define DHID 4096
#define ND9 9216
#define ROWS (BB*TT)

using bf16 = __hip_bfloat16;
typedef short bf16x8 __attribute__((ext_vector_type(8)));
typedef float f32x4 __attribute__((ext_vector_type(4)));
typedef unsigned short u16;

__device__ __forceinline__ float b2f(bf16 v){ return __bfloat162float(v); }
__device__ __forceinline__ bf16 f2b(float v){ return __float2bfloat16(v); }
__device__ __forceinline__ u16 fb(float v){              // float -> bf16 bits (RNE)
    unsigned u = __float_as_uint(v);
    u += 0x7fffu + ((u >> 16) & 1u);
    return (u16)(u >> 16);
}
__device__ __forceinline__ void gl_lds16(const u16* g, u16* l) {
    __builtin_amdgcn_global_load_lds(
        (const __attribute__((address_space(1))) unsigned int*)g,
        (__attribute__((address_space(3))) unsigned int*)l, 16, 0, 0);
}

// ---------------- mod = silu(c) @ ada_w + ada_b  (4 rows x 9216) ----------------
__global__ void ada_kernel(const float* __restrict__ c, const float* __restrict__ ada_w,
                           const float* __restrict__ ada_b, float* __restrict__ mod) {
    __shared__ float sc_[4][DD];
    int n = blockIdx.x * 256 + threadIdx.x;
    for (int idx = threadIdx.x; idx < 4*DD; idx += 256) {
        int r = idx >> 10, k = idx & 1023;
        float v = c[r*DD + k];
        sc_[r][k] = v / (1.f + __expf(-v));
    }
    __syncthreads();
    float a0=0.f, a1=0.f, a2=0.f, a3=0.f;
    for (int k = 0; k < DD; ++k) {
        float wv = ada_w[(size_t)k*ND9 + n];
        a0 += sc_[0][k]*wv; a1 += sc_[1][k]*wv; a2 += sc_[2][k]*wv; a3 += sc_[3][k]*wv;
    }
    float bb = ada_b[n];
    mod[0*(size_t)ND9+n]=a0+bb; mod[1*(size_t)ND9+n]=a1+bb;
    mod[2*(size_t)ND9+n]=a2+bb; mod[3*(size_t)ND9+n]=a3+bb;
}

// ---------------- resid(out) = copy(x) ----------------
__global__ void cast_x(const float* __restrict__ x, float* __restrict__ xc, int n) {
    int i = blockIdx.x * 256 + threadIdx.x;
    if (i < n) xc[i] = x[i];
}

// ---------------- W (KxN f32) -> Wt (NxK bf16 bits) ----------------
__global__ void transpose_w(const float* __restrict__ W, u16* __restrict__ Wt, int K, int N) {
    __shared__ float T[32][33];
    int n0 = blockIdx.x * 32, k0 = blockIdx.y * 32;
    int lx = threadIdx.x & 31, ly = threadIdx.x >> 5;
    #pragma unroll
    for (int i = 0; i < 4; ++i)
        T[ly + i*8][lx] = W[(size_t)(k0 + ly + i*8)*N + n0 + lx];
    __syncthreads();
    #pragma unroll
    for (int i = 0; i < 4; ++i) {
        int n = ly + i*8;
        Wt[(size_t)(n0 + n)*K + k0 + lx] = fb(T[lx][n]);
    }
}

// ---------------- V slice of qkv -> vt[bh*16+head][d][key]  (bf16) ----------------
__global__ void vtrans(const u16* __restrict__ qkv, u16* __restrict__ vt) {
    __shared__ u16 T[64][72];
    int kt = blockIdx.x;        // 16 key tiles
    int gh = blockIdx.y;        // 64 = bh*16+head
    int tid = threadIdx.x;
    int key = tid >> 2, c8 = (tid & 3) * 16;
    const u16* src = qkv + (size_t)((gh >> 4)*1024 + kt*64 + key)*3072 + 2048 + (gh & 15)*64 + c8;
    *(uint4*)&T[key][c8]     = *(const uint4*)src;
    *(uint4*)&T[key][c8 + 8] = *(const uint4*)(src + 8);
    __syncthreads();
    int d = tid >> 2, kc = (tid & 3) * 16;
    u16 tmp[16];
    #pragma unroll
    for (int i = 0; i < 16; ++i) tmp[i] = T[kc + i][d];
    u16* dst = vt + ((size_t)gh*64 + d)*1024 + kt*64 + kc;
    *(uint4*)&dst[0] = *(const uint4*)&tmp[0];
    *(uint4*)&dst[8] = *(const uint4*)&tmp[8];
}

// ---------------- y = mod(ln(src), shift, scale) as bf16 ----------------
__global__ void ln_mod_kernel(const float* __restrict__ xc, const float* __restrict__ mod,
                              int jshift, int jscale, bf16* __restrict__ y) {
    int row = blockIdx.x;
    int b = row / TT, t = row % TT;
    int cz = (t >= HALF) ? 1 : 0;
    const float* mp = mod + (size_t)(b*2 + cz) * ND9;
    const float* xr = xc + (size_t)row * DD;
    int tid = threadIdx.x;
    float v[4];
    float s = 0.f, ss = 0.f;
    #pragma unroll
    for (int i = 0; i < 4; ++i) {
        v[i] = xr[tid + i*256];
        s += v[i]; ss += v[i]*v[i];
    }
    __shared__ float red[256];
    red[tid] = s; __syncthreads();
    for (int o = 128; o > 0; o >>= 1) { if (tid < o) red[tid] += red[tid+o]; __syncthreads(); }
    float mean = red[0] * (1.f/DD);
    __syncthreads();
    red[tid] = ss; __syncthreads();
    for (int o = 128; o > 0; o >>= 1) { if (tid < o) red[tid] += red[tid+o]; __syncthreads(); }
    float var = red[0] * (1.f/DD) - mean*mean;
    float rstd = rsqrtf(var + 1e-6f);
    bf16* yr = y + (size_t)row * DD;
    #pragma unroll
    for (int i = 0; i < 4; ++i) {
        int d = tid + i*256;
        float sh = mp[jshift*DD + d], sc2 = mp[jscale*DD + d];
        yr[d] = f2b((v[i] - mean) * rstd * (1.f + sc2) + sh);
    }
}

// ---------------- MFMA GEMM (m97-style): 128x128 tile, BK=32, global_load_lds ----------------
// epi 0: out = bf16(v); epi 1: out = bf16(gelu_tanh(v));
// epi 2: resid_out[m*N+n] = resid_in[m*N+n] + mod_g*v  (N == DD)
__global__ __launch_bounds__(256, 2) void gemm_mfma(
    const u16* __restrict__ A, const u16* __restrict__ Wt, const float* __restrict__ bias,
    u16* __restrict__ out, const float* __restrict__ resid_in, float* __restrict__ resid_out,
    const float* __restrict__ mod, int jg, int m_base, int a_off, int o_off,
    int K, int N, int epi)
{
    __shared__ u16 As[128*32];
    __shared__ u16 Bs[128*32];
    int tid = threadIdx.x;
    int w = tid >> 6, lane = tid & 63;
    int quad = lane >> 4, l16 = lane & 15;
    int m0 = m_base + blockIdx.y * 128;
    int n0 = blockIdx.x * 128;
    int wr = (w & 1) * 64, wc = (w >> 1) * 64;

    f32x4 acc[4][4];
    #pragma unroll
    for (int i = 0; i < 4; ++i)
        #pragma unroll
        for (int j = 0; j < 4; ++j) acc[i][j] = (f32x4){0.f,0.f,0.f,0.f};

    const u16* Ag = A + (size_t)(m0 - a_off) * K;
    const u16* Bg = Wt + (size_t)n0 * K;
    int srow = lane >> 2, scol = (lane & 3) * 8;   // lane i -> chunk offset 16*i bytes
    int c0 = w*2, c1 = w*2 + 1;

    for (int k0 = 0; k0 < K; k0 += 32) {
        gl_lds16(Ag + (size_t)(c0*16 + srow)*K + k0 + scol, As + c0*512);
        gl_lds16(Ag + (size_t)(c1*16 + srow)*K + k0 + scol, As + c1*512);
        gl_lds16(Bg + (size_t)(c0*16 + srow)*K + k0 + scol, Bs + c0*512);
        gl_lds16(Bg + (size_t)(c1*16 + srow)*K + k0 + scol, Bs + c1*512);
        __syncthreads();
        bf16x8 af[4], bfr[4];
        #pragma unroll
        for (int i = 0; i < 4; ++i) af[i] = *(const bf16x8*)&As[(wr + i*16 + l16)*32 + quad*8];
        #pragma unroll
        for (int j = 0; j < 4; ++j) bfr[j] = *(const bf16x8*)&Bs[(wc + j*16 + l16)*32 + quad*8];
        #pragma unroll
        for (int i = 0; i < 4; ++i)
            #pragma unroll
            for (int j = 0; j < 4; ++j)
                acc[i][j] = __builtin_amdgcn_mfma_f32_16x16x32_bf16(af[i], bfr[j], acc[i][j], 0, 0, 0);
        __syncthreads();
    }

    #pragma unroll
    for (int i = 0; i < 4; ++i) {
        #pragma unroll
        for (int r = 0; r < 4; ++r) {
            int mm = m0 + wr + i*16 + quad*4 + r;
            int brow = mm / TT, tt2 = mm % TT;
            int cz = (tt2 >= HALF) ? 1 : 0;
            const float* mp = (epi == 2) ? (mod + (size_t)(brow*2 + cz)*ND9 + (size_t)jg*DD) : nullptr;
            #pragma unroll
            for (int j = 0; j < 4; ++j) {
                int n = n0 + wc + j*16 + l16;
                float v = acc[i][j][r] + bias[n];
                if (epi == 0) {
                    out[(size_t)(mm - o_off)*N + n] = fb(v);
                } else if (epi == 1) {
                    float u = v;
                    float g = 0.5f*u*(1.f + tanhf(0.7978845608028654f*(u + 0.044715f*u*u*u)));
                    out[(size_t)(mm - o_off)*N + n] = fb(g);
                } else {
                    size_t idx = (size_t)mm*N + n;
                    resid_out[idx] = resid_in[idx] + mp[n]*v;
                }
            }
        }
    }
}

// ---------------- MFMA flash attention, both batches in one dispatch ----------------
// qkv rows 0..4095 (= bh*1024 + t), stride 3072: q|k|v at cols 0|1024|2048 (+head*64)
// vt: [bh*16+head][64 d][1024 key]; grid (16 qtiles, NH, 4 bh); block 256 = 4 waves
__global__ __launch_bounds__(256) void attn_mfma(const u16* __restrict__ qkv,
                                                 const u16* __restrict__ vt,
                                                 u16* __restrict__ attn_out, int kv_swap) {
    __shared__ u16 Ks[64][72];       // [key][d]
    __shared__ u16 Vs[64][72];       // [d][key]
    __shared__ u16 Ps[4][16][72];    // per-wave P: [qrow][key]
    int qt = blockIdx.x, head = blockIdx.y, bh = blockIdx.z;
    int kvbh = kv_swap ? (bh ^ 1) : bh;
    int tid = threadIdx.x;
    int w = tid >> 6, lane = tid & 63;
    int quad = lane >> 4, l16 = lane & 15;
    int qrow0 = bh*1024 + qt*64 + w*16;

    const u16* qp = qkv + (size_t)(qrow0 + l16)*3072 + head*64;
    bf16x8 qa0 = *(const bf16x8*)(qp + quad*8);
    bf16x8 qa1 = *(const bf16x8*)(qp + 32 + quad*8);

    f32x4 oacc[4];
    #pragma unroll
    for (int i = 0; i < 4; ++i) oacc[i] = (f32x4){0.f,0.f,0.f,0.f};
    float mst[4], lst[4];
    #pragma unroll
    for (int r = 0; r < 4; ++r) { mst[r] = -3e38f; lst[r] = 0.f; }

    int skey = tid >> 2, sc8 = (tid & 3) * 16;
    const u16* kbase = qkv + (size_t)(kvbh*1024 + skey)*3072 + 1024 + head*64 + sc8;
    const u16* vbase = vt + ((size_t)(kvbh*16 + head)*64 + skey)*1024 + sc8;

    for (int kt = 0; kt < 16; ++kt) {
        __syncthreads();
        const u16* kp = kbase + (size_t)kt*64*3072;
        *(uint4*)&Ks[skey][sc8]     = *(const uint4*)kp;
        *(uint4*)&Ks[skey][sc8 + 8] = *(const uint4*)(kp + 8);
        const u16* vp = vbase + kt*64;
        *(uint4*)&Vs[skey][sc8]     = *(const uint4*)vp;
        *(uint4*)&Vs[skey][sc8 + 8] = *(const uint4*)(vp + 8);
        __syncthreads();

        f32x4 sacc[4];
        #pragma unroll
        for (int nt = 0; nt < 4; ++nt) sacc[nt] = (f32x4){0.f,0.f,0.f,0.f};
        #pragma unroll
        for (int nt = 0; nt < 4; ++nt) {
            bf16x8 kb0 = *(const bf16x8*)&Ks[nt*16 + l16][quad*8];
            bf16x8 kb1 = *(const bf16x8*)&Ks[nt*16 + l16][32 + quad*8];
            sacc[nt] = __builtin_amdgcn_mfma_f32_16x16x32_bf16(qa0, kb0, sacc[nt], 0, 0, 0);
            sacc[nt] = __builtin_amdgcn_mfma_f32_16x16x32_bf16(qa1, kb1, sacc[nt], 0, 0, 0);
        }
        #pragma unroll
        for (int r = 0; r < 4; ++r) {
            float sv0 = sacc[0][r]*0.125f, sv1 = sacc[1][r]*0.125f;
            float sv2 = sacc[2][r]*0.125f, sv3 = sacc[3][r]*0.125f;
            float mx = fmaxf(fmaxf(sv0, sv1), fmaxf(sv2, sv3));
            #pragma unroll
            for (int o = 1; o < 16; o <<= 1) mx = fmaxf(mx, __shfl_xor(mx, o));
            float mnew = fmaxf(mst[r], mx);
            float alpha = __expf(mst[r] - mnew);
            float p0 = __expf(sv0 - mnew), p1 = __expf(sv1 - mnew);
            float p2 = __expf(sv2 - mnew), p3 = __expf(sv3 - mnew);
            float ls = p0 + p1 + p2 + p3;
            #pragma unroll
            for (int o = 1; o < 16; o <<= 1) ls += __shfl_xor(ls, o);
            lst[r] = lst[r]*alpha + ls;
            mst[r] = mnew;
            #pragma unroll
            for (int dt = 0; dt < 4; ++dt) oacc[dt][r] *= alpha;
            int qr = quad*4 + r;
            Ps[w][qr][ 0 + l16] = fb(p0);
            Ps[w][qr][16 + l16] = fb(p1);
            Ps[w][qr][32 + l16] = fb(p2);
            Ps[w][qr][48 + l16] = fb(p3);
        }
        bf16x8 pa0 = *(const bf16x8*)&Ps[w][l16][quad*8];
        bf16x8 pa1 = *(const bf16x8*)&Ps[w][l16][32 + quad*8];
        #pragma unroll
        for (int dt = 0; dt < 4; ++dt) {
            bf16x8 vb0 = *(const bf16x8*)&Vs[dt*16 + l16][quad*8];
            bf16x8 vb1 = *(const bf16x8*)&Vs[dt*16 + l16][32 + quad*8];
            oacc[dt] = __builtin_amdgcn_mfma_f32_16x16x32_bf16(pa0, vb0, oacc[dt], 0, 0, 0);
            oacc[dt] = __builtin_amdgcn_mfma_f32_16x16x32_bf16(pa1, vb1, oacc[dt], 0, 0, 0);
        }
    }
    #pragma unroll
    for (int dt = 0; dt < 4; ++dt)
        #pragma unroll
        for (int r = 0; r < 4; ++r)
            attn_out[(size_t)(qrow0 + quad*4 + r)*DD + head*64 + dt*16 + l16] = fb(oacc[dt][r] / lst[r]);
}

extern "C" void kernel_launch(void* const* d_in, const int* in_sizes, int n_in,
                              void* d_out, int out_size, void* d_ws, size_t ws_size,
                              hipStream_t stream) {
    const float* x          = (const float*)d_in[0];
    const float* c          = (const float*)d_in[1];
    const float* attn_qkv_w = (const float*)d_in[2];
    const float* attn_qkv_b = (const float*)d_in[3];
    const float* attn_proj_w= (const float*)d_in[4];
    const float* attn_proj_b= (const float*)d_in[5];
    const float* crs_qkv_w  = (const float*)d_in[6];
    const float* crs_qkv_b  = (const float*)d_in[7];
    const float* crs_proj_w = (const float*)d_in[8];
    const float* crs_proj_b = (const float*)d_in[9];
    const float* fc1_w      = (const float*)d_in[10];
    const float* fc1_b      = (const float*)d_in[11];
    const float* fc2_w      = (const float*)d_in[12];
    const float* fc2_b      = (const float*)d_in[13];
    const float* ada_w      = (const float*)d_in[14];
    const float* ada_b      = (const float*)d_in[15];
    float* out = (float*)d_out;     // f32 running residual (= x; MSA branch excluded per reference)

    // ws regions (total 56.25 MB, time-multiplexed; liveness traced per dispatch)
    char* ws = (char*)d_ws;
    float* mod = (float*)ws;                       // 0.25 MB
    char* R1   = ws + (256u<<10);                  // 16 MB
    char* Yr   = R1 + (16u<<20);                   // 8 MB
    char* AOr  = Yr + (8u<<20);                    // 8 MB
    char* BIGr = AOr + (8u<<20);                   // 24 MB

    float* x0x1  = (float*)R1;                     // 16 MB (MSA-proj -> MCA-ln)
    u16*   wt_a  = (u16*)R1;                       // qkv weight transpose, 6 MB
    u16*   vt    = (u16*)(R1 + (8u<<20));          // 8 MB V-transpose (during attn)
    bf16*  y     = (bf16*)Yr;                      // ln output, 8 MB
    u16*   wt_p  = (u16*)Yr;                       // proj weight transpose, 2 MB
    u16*   attn_o= (u16*)AOr;                      // 8 MB
    u16*   hstage= (u16*)AOr;                      // fc1 output chunk, 8 MB (attn_o dead)
    u16*   big   = (u16*)BIGr;                     // qkv both batches, 24 MB
    u16*   fc1_t = (u16*)R1;                       // 8 MB
    u16*   fc2_t = (u16*)(R1 + (8u<<20));          // 8 MB

    ada_kernel<<<dim3(ND9/256), 256, 0, stream>>>(c, ada_w, ada_b, mod);
    cast_x<<<(ROWS*DD)/256, 256, 0, stream>>>(x, out, ROWS*DD);

    // ================= MSA =================
    transpose_w<<<dim3(3*DD/32, DD/32), 256, 0, stream>>>(attn_qkv_w, wt_a, DD, 3*DD);
    ln_mod_kernel<<<ROWS, 256, 0, stream>>>(out, mod, 0, 1, y);
    gemm_mfma<<<dim3(3*DD/128, ROWS/128), 256, 0, stream>>>((const u16*)y, wt_a, attn_qkv_b,
                                                            big, nullptr, nullptr, nullptr, 0,
                                                            0, 0, 0, DD, 3*DD, 0);
    vtrans<<<dim3(16, 64), 256, 0, stream>>>(big, vt);
    attn_mfma<<<dim3(16, NH, 4), 256, 0, stream>>>(big, vt, attn_o, 0);
    transpose_w<<<dim3(DD/32, DD/32), 256, 0, stream>>>(attn_proj_w, wt_p, DD, DD);
    // x0x1 = out + g_msa * proj(attn_o)   (overwrites R1: wt_a/vt dead)
    gemm_mfma<<<dim3(DD/128, ROWS/128), 256, 0, stream>>>(attn_o, wt_p, attn_proj_b,
                                                          nullptr, out, x0x1, mod, 2,
                                                          0, 0, 0, DD, DD, 2);

    // ================= MCA =================
    ln_mod_kernel<<<ROWS, 256, 0, stream>>>(x0x1, mod, 3, 4, y);   // consumes x0x1 BEFORE R1 reuse
    transpose_w<<<dim3(3*DD/32, DD/32), 256, 0, stream>>>(crs_qkv_w, wt_a, DD, 3*DD);
    gemm_mfma<<<dim3(3*DD/128, ROWS/128), 256, 0, stream>>>((const u16*)y, wt_a, crs_qkv_b,
                                                            big, nullptr, nullptr, nullptr, 0,
                                                            0, 0, 0, DD, 3*DD, 0);
    vtrans<<<dim3(16, 64), 256, 0, stream>>>(big, vt);
    attn_mfma<<<dim3(16, NH, 4), 256, 0, stream>>>(big, vt, attn_o, 1);
    transpose_w<<<dim3(DD/32, DD/32), 256, 0, stream>>>(crs_proj_w, wt_p, DD, DD);
    gemm_mfma<<<dim3(DD/128, ROWS/128), 256, 0, stream>>>(attn_o, wt_p, crs_proj_b,
                                                          nullptr, out, out, mod, 5,
                                                          0, 0, 0, DD, DD, 2);

    // ================= MLP =================
    ln_mod_kernel<<<ROWS, 256, 0, stream>>>(out, mod, 6, 7, y);
    transpose_w<<<dim3(DHID/32, DD/32), 256, 0, stream>>>(fc1_w, fc1_t, DD, DHID);
    transpose_w<<<dim3(DD/32, DHID/32), 256, 0, stream>>>(fc2_w, fc2_t, DHID, DD);
    for (int ch = 0; ch < 4; ++ch) {
        int r0 = ch * 1024;
        gemm_mfma<<<dim3(DHID/128, 1024/128), 256, 0, stream>>>((const u16*)y, fc1_t, fc1_b,
                                                                hstage, nullptr, nullptr, nullptr, 0,
                                                                r0, 0, r0, DD, DHID, 1);
        gemm_mfma<<<dim3(DD/128, 1024/128), 256, 0, stream>>>(hstage, fc2_t, fc2_b,
                                                              nullptr, out, out, mod, 8,
                                                              r0, r0, 0, DHID, DD, 2);
    }
}

// Round 8
// 627.795 us; speedup vs baseline: 13.2499x; 1.7362x over previous
//
#include <hip/hip_runtime.h>
#include <hip/hip_bf16.h>

#define BB 2
#define TT 2048
#define DD 1024
#define NH 16
#define HALF 1024
#define DHID 4096
#define ND9 9216
#define ROWS (BB*TT)

using bf16 = __hip_bfloat16;
typedef short bf16x8 __attribute__((ext_vector_type(8)));
typedef float f32x4 __attribute__((ext_vector_type(4)));
typedef unsigned short u16;

__device__ __forceinline__ float b2f(bf16 v){ return __bfloat162float(v); }
__device__ __forceinline__ bf16 f2b(float v){ return __float2bfloat16(v); }
__device__ __forceinline__ float bits2f(u16 b){ return __uint_as_float(((unsigned)b) << 16); }
__device__ __forceinline__ u16 fb(float v){              // float -> bf16 bits (RNE)
    unsigned u = __float_as_uint(v);
    u += 0x7fffu + ((u >> 16) & 1u);
    return (u16)(u >> 16);
}
__device__ __forceinline__ void gl_lds16(const u16* g, u16* l) {
    __builtin_amdgcn_global_load_lds(
        (const __attribute__((address_space(1))) unsigned int*)g,
        (__attribute__((address_space(3))) unsigned int*)l, 16, 0, 0);
}

// ---------------- ada stage 1: partial[s][r][n] over 64-k slices ----------------
__global__ void ada_part(const float* __restrict__ c, const float* __restrict__ ada_w,
                         float* __restrict__ part) {
    __shared__ float sc_[4][64];
    int s = blockIdx.y;                      // 0..15
    int k0 = s * 64;
    int n0 = blockIdx.x * 1024 + threadIdx.x * 4;
    {
        int r = threadIdx.x >> 6, k = threadIdx.x & 63;
        float v = c[r*DD + k0 + k];
        sc_[r][k] = v / (1.f + __expf(-v));
    }
    __syncthreads();
    float4 a0 = {0,0,0,0}, a1 = {0,0,0,0}, a2 = {0,0,0,0}, a3 = {0,0,0,0};
    for (int k = 0; k < 64; ++k) {
        float4 wv = *(const float4*)&ada_w[(size_t)(k0 + k)*ND9 + n0];
        float s0 = sc_[0][k], s1 = sc_[1][k], s2 = sc_[2][k], s3 = sc_[3][k];
        a0.x += s0*wv.x; a0.y += s0*wv.y; a0.z += s0*wv.z; a0.w += s0*wv.w;
        a1.x += s1*wv.x; a1.y += s1*wv.y; a1.z += s1*wv.z; a1.w += s1*wv.w;
        a2.x += s2*wv.x; a2.y += s2*wv.y; a2.z += s2*wv.z; a2.w += s2*wv.w;
        a3.x += s3*wv.x; a3.y += s3*wv.y; a3.z += s3*wv.z; a3.w += s3*wv.w;
    }
    *(float4*)&part[((size_t)(s*4 + 0))*ND9 + n0] = a0;
    *(float4*)&part[((size_t)(s*4 + 1))*ND9 + n0] = a1;
    *(float4*)&part[((size_t)(s*4 + 2))*ND9 + n0] = a2;
    *(float4*)&part[((size_t)(s*4 + 3))*ND9 + n0] = a3;
}

// ---------------- ada stage 2: mod[r][n] = sum_s part + bias ----------------
__global__ void ada_reduce(const float* __restrict__ part, const float* __restrict__ ada_b,
                           float* __restrict__ mod) {
    int g = blockIdx.x * 1024 + threadIdx.x * 4;    // over [0, 4*ND9)
    int r = g / ND9, n = g - r*ND9;
    float4 acc = *(const float4*)&ada_b[n];
    #pragma unroll
    for (int s = 0; s < 16; ++s) {
        float4 p = *(const float4*)&part[((size_t)(s*4 + r))*ND9 + n];
        acc.x += p.x; acc.y += p.y; acc.z += p.z; acc.w += p.w;
    }
    *(float4*)&mod[(size_t)r*ND9 + n] = acc;
}

// ---------------- resid(out) = copy(x), float4 ----------------
__global__ void cast_x4(const float* __restrict__ x, float* __restrict__ xc) {
    int i = (blockIdx.x * 256 + threadIdx.x) * 4;
    *(float4*)&xc[i] = *(const float4*)&x[i];
}

// ---------------- dst = src + bf16(gv), float4 ----------------
__global__ void resid_add(const float* __restrict__ src, const u16* __restrict__ gv,
                          float* __restrict__ dst) {
    int i = (blockIdx.x * 256 + threadIdx.x) * 4;
    float4 s = *(const float4*)&src[i];
    ushort4 g = *(const ushort4*)&gv[i];
    float4 o;
    o.x = s.x + bits2f(g.x); o.y = s.y + bits2f(g.y);
    o.z = s.z + bits2f(g.z); o.w = s.w + bits2f(g.w);
    *(float4*)&dst[i] = o;
}

// ---------------- W (KxN f32) -> Wt (NxK bf16 bits) ----------------
__global__ void transpose_w(const float* __restrict__ W, u16* __restrict__ Wt, int K, int N) {
    __shared__ float T[32][33];
    int n0 = blockIdx.x * 32, k0 = blockIdx.y * 32;
    int lx = threadIdx.x & 31, ly = threadIdx.x >> 5;
    #pragma unroll
    for (int i = 0; i < 4; ++i)
        T[ly + i*8][lx] = W[(size_t)(k0 + ly + i*8)*N + n0 + lx];
    __syncthreads();
    #pragma unroll
    for (int i = 0; i < 4; ++i) {
        int n = ly + i*8;
        Wt[(size_t)(n0 + n)*K + k0 + lx] = fb(T[lx][n]);
    }
}

// ---------------- V slice of qkv -> vt[bh*16+head][d][key] ----------------
__global__ void vtrans(const u16* __restrict__ qkv, u16* __restrict__ vt) {
    __shared__ u16 T[64][72];
    int kt = blockIdx.x;
    int gh = blockIdx.y;
    int tid = threadIdx.x;
    int key = tid >> 2, c8 = (tid & 3) * 16;
    const u16* src = qkv + (size_t)((gh >> 4)*1024 + kt*64 + key)*3072 + 2048 + (gh & 15)*64 + c8;
    *(uint4*)&T[key][c8]     = *(const uint4*)src;
    *(uint4*)&T[key][c8 + 8] = *(const uint4*)(src + 8);
    __syncthreads();
    int d = tid >> 2, kc = (tid & 3) * 16;
    u16 tmp[16];
    #pragma unroll
    for (int i = 0; i < 16; ++i) tmp[i] = T[kc + i][d];
    u16* dst = vt + ((size_t)gh*64 + d)*1024 + kt*64 + kc;
    *(uint4*)&dst[0] = *(const uint4*)&tmp[0];
    *(uint4*)&dst[8] = *(const uint4*)&tmp[8];
}

// ---------------- y = mod(ln(src), shift, scale) as bf16 ----------------
__global__ void ln_mod_kernel(const float* __restrict__ xc, const float* __restrict__ mod,
                              int jshift, int jscale, bf16* __restrict__ y) {
    int row = blockIdx.x;
    int b = row / TT, t = row % TT;
    int cz = (t >= HALF) ? 1 : 0;
    const float* mp = mod + (size_t)(b*2 + cz) * ND9;
    const float* xr = xc + (size_t)row * DD;
    int tid = threadIdx.x;
    float v[4];
    float s = 0.f, ss = 0.f;
    #pragma unroll
    for (int i = 0; i < 4; ++i) {
        v[i] = xr[tid + i*256];
        s += v[i]; ss += v[i]*v[i];
    }
    __shared__ float red[256];
    red[tid] = s; __syncthreads();
    for (int o = 128; o > 0; o >>= 1) { if (tid < o) red[tid] += red[tid+o]; __syncthreads(); }
    float mean = red[0] * (1.f/DD);
    __syncthreads();
    red[tid] = ss; __syncthreads();
    for (int o = 128; o > 0; o >>= 1) { if (tid < o) red[tid] += red[tid+o]; __syncthreads(); }
    float var = red[0] * (1.f/DD) - mean*mean;
    float rstd = rsqrtf(var + 1e-6f);
    bf16* yr = y + (size_t)row * DD;
    #pragma unroll
    for (int i = 0; i < 4; ++i) {
        int d = tid + i*256;
        float sh = mp[jshift*DD + d], sc2 = mp[jscale*DD + d];
        yr[d] = f2b((v[i] - mean) * rstd * (1.f + sc2) + sh);
    }
}

// ---------------- epilogue helper ----------------
__device__ __forceinline__ void epi_store(u16* out, int o_off, int N, int mm, int n, float v,
                                          const float* mod, int jg, int epi) {
    if (epi == 0) {
        out[(size_t)(mm - o_off)*N + n] = fb(v);
    } else if (epi == 1) {
        float u = v;
        float g = 0.5f*u*(1.f + tanhf(0.7978845608028654f*(u + 0.044715f*u*u*u)));
        out[(size_t)(mm - o_off)*N + n] = fb(g);
    } else {
        int brow = mm / TT, tt2 = mm % TT;
        int cz = (tt2 >= HALF) ? 1 : 0;
        const float* mp = mod + (size_t)(brow*2 + cz)*ND9 + (size_t)jg*DD;
        out[(size_t)(mm - o_off)*N + n] = fb(mp[n]*v);
    }
}

// ---------------- MFMA GEMM 128x128 tile, BK=32, global_load_lds ----------------
__global__ __launch_bounds__(256, 2) void gemm_mfma(
    const u16* __restrict__ A, const u16* __restrict__ Wt, const float* __restrict__ bias,
    u16* __restrict__ out, const float* __restrict__ mod, int jg,
    int m_base, int a_off, int o_off, int K, int N, int epi)
{
    __shared__ u16 As[128*32];
    __shared__ u16 Bs[128*32];
    int tid = threadIdx.x;
    int w = tid >> 6, lane = tid & 63;
    int quad = lane >> 4, l16 = lane & 15;
    int m0 = m_base + blockIdx.y * 128;
    int n0 = blockIdx.x * 128;
    int wr = (w & 1) * 64, wc = (w >> 1) * 64;

    f32x4 acc[4][4];
    #pragma unroll
    for (int i = 0; i < 4; ++i)
        #pragma unroll
        for (int j = 0; j < 4; ++j) acc[i][j] = (f32x4){0.f,0.f,0.f,0.f};

    const u16* Ag = A + (size_t)(m0 - a_off) * K;
    const u16* Bg = Wt + (size_t)n0 * K;
    int srow = lane >> 2, scol = (lane & 3) * 8;
    int c0 = w*2, c1 = w*2 + 1;

    for (int k0 = 0; k0 < K; k0 += 32) {
        gl_lds16(Ag + (size_t)(c0*16 + srow)*K + k0 + scol, As + c0*512);
        gl_lds16(Ag + (size_t)(c1*16 + srow)*K + k0 + scol, As + c1*512);
        gl_lds16(Bg + (size_t)(c0*16 + srow)*K + k0 + scol, Bs + c0*512);
        gl_lds16(Bg + (size_t)(c1*16 + srow)*K + k0 + scol, Bs + c1*512);
        __syncthreads();
        bf16x8 af[4], bfr[4];
        #pragma unroll
        for (int i = 0; i < 4; ++i) af[i] = *(const bf16x8*)&As[(wr + i*16 + l16)*32 + quad*8];
        #pragma unroll
        for (int j = 0; j < 4; ++j) bfr[j] = *(const bf16x8*)&Bs[(wc + j*16 + l16)*32 + quad*8];
        #pragma unroll
        for (int i = 0; i < 4; ++i)
            #pragma unroll
            for (int j = 0; j < 4; ++j)
                acc[i][j] = __builtin_amdgcn_mfma_f32_16x16x32_bf16(af[i], bfr[j], acc[i][j], 0, 0, 0);
        __syncthreads();
    }

    #pragma unroll
    for (int i = 0; i < 4; ++i)
        #pragma unroll
        for (int r = 0; r < 4; ++r) {
            int mm = m0 + wr + i*16 + quad*4 + r;
            #pragma unroll
            for (int j = 0; j < 4; ++j) {
                int n = n0 + wc + j*16 + l16;
                epi_store(out, o_off, N, mm, n, acc[i][j][r] + bias[n], mod, jg, epi);
            }
        }
}

// ---------------- MFMA GEMM 64x128 tile (narrow-N), BK=32 ----------------
__global__ __launch_bounds__(256, 2) void gemm64(
    const u16* __restrict__ A, const u16* __restrict__ Wt, const float* __restrict__ bias,
    u16* __restrict__ out, const float* __restrict__ mod, int jg,
    int m_base, int a_off, int o_off, int K, int N, int epi)
{
    __shared__ u16 As[64*32];
    __shared__ u16 Bs[128*32];
    int tid = threadIdx.x;
    int w = tid >> 6, lane = tid & 63;
    int quad = lane >> 4, l16 = lane & 15;
    int m0 = m_base + blockIdx.y * 64;
    int n0 = blockIdx.x * 128;

    f32x4 acc[4][2];
    #pragma unroll
    for (int i = 0; i < 4; ++i)
        #pragma unroll
        for (int j = 0; j < 2; ++j) acc[i][j] = (f32x4){0.f,0.f,0.f,0.f};

    const u16* Ag = A + (size_t)(m0 - a_off) * K;
    const u16* Bg = Wt + (size_t)n0 * K;
    int srow = lane >> 2, scol = (lane & 3) * 8;

    for (int k0 = 0; k0 < K; k0 += 32) {
        gl_lds16(Ag + (size_t)(w*16 + srow)*K + k0 + scol, As + w*512);
        gl_lds16(Bg + (size_t)((w*2)*16 + srow)*K + k0 + scol, Bs + (w*2)*512);
        gl_lds16(Bg + (size_t)((w*2+1)*16 + srow)*K + k0 + scol, Bs + (w*2+1)*512);
        __syncthreads();
        bf16x8 af[4], bfr[2];
        #pragma unroll
        for (int i = 0; i < 4; ++i) af[i] = *(const bf16x8*)&As[(i*16 + l16)*32 + quad*8];
        #pragma unroll
        for (int j = 0; j < 2; ++j) bfr[j] = *(const bf16x8*)&Bs[(w*32 + j*16 + l16)*32 + quad*8];
        #pragma unroll
        for (int i = 0; i < 4; ++i)
            #pragma unroll
            for (int j = 0; j < 2; ++j)
                acc[i][j] = __builtin_amdgcn_mfma_f32_16x16x32_bf16(af[i], bfr[j], acc[i][j], 0, 0, 0);
        __syncthreads();
    }

    #pragma unroll
    for (int i = 0; i < 4; ++i)
        #pragma unroll
        for (int r = 0; r < 4; ++r) {
            int mm = m0 + i*16 + quad*4 + r;
            #pragma unroll
            for (int j = 0; j < 2; ++j) {
                int n = n0 + w*32 + j*16 + l16;
                epi_store(out, o_off, N, mm, n, acc[i][j][r] + bias[n], mod, jg, epi);
            }
        }
}

// ---------------- MFMA flash attention, both batches in one dispatch ----------------
__global__ __launch_bounds__(256) void attn_mfma(const u16* __restrict__ qkv,
                                                 const u16* __restrict__ vt,
                                                 u16* __restrict__ attn_out, int kv_swap) {
    __shared__ u16 Ks[64][72];
    __shared__ u16 Vs[64][72];
    __shared__ u16 Ps[4][16][72];
    int qt = blockIdx.x, head = blockIdx.y, bh = blockIdx.z;
    int kvbh = kv_swap ? (bh ^ 1) : bh;
    int tid = threadIdx.x;
    int w = tid >> 6, lane = tid & 63;
    int quad = lane >> 4, l16 = lane & 15;
    int qrow0 = bh*1024 + qt*64 + w*16;

    const u16* qp = qkv + (size_t)(qrow0 + l16)*3072 + head*64;
    bf16x8 qa0 = *(const bf16x8*)(qp + quad*8);
    bf16x8 qa1 = *(const bf16x8*)(qp + 32 + quad*8);

    f32x4 oacc[4];
    #pragma unroll
    for (int i = 0; i < 4; ++i) oacc[i] = (f32x4){0.f,0.f,0.f,0.f};
    float mst[4], lst[4];
    #pragma unroll
    for (int r = 0; r < 4; ++r) { mst[r] = -3e38f; lst[r] = 0.f; }

    int skey = tid >> 2, sc8 = (tid & 3) * 16;
    const u16* kbase = qkv + (size_t)(kvbh*1024 + skey)*3072 + 1024 + head*64 + sc8;
    const u16* vbase = vt + ((size_t)(kvbh*16 + head)*64 + skey)*1024 + sc8;

    for (int kt = 0; kt < 16; ++kt) {
        __syncthreads();
        const u16* kp = kbase + (size_t)kt*64*3072;
        *(uint4*)&Ks[skey][sc8]     = *(const uint4*)kp;
        *(uint4*)&Ks[skey][sc8 + 8] = *(const uint4*)(kp + 8);
        const u16* vp = vbase + kt*64;
        *(uint4*)&Vs[skey][sc8]     = *(const uint4*)vp;
        *(uint4*)&Vs[skey][sc8 + 8] = *(const uint4*)(vp + 8);
        __syncthreads();

        f32x4 sacc[4];
        #pragma unroll
        for (int nt = 0; nt < 4; ++nt) sacc[nt] = (f32x4){0.f,0.f,0.f,0.f};
        #pragma unroll
        for (int nt = 0; nt < 4; ++nt) {
            bf16x8 kb0 = *(const bf16x8*)&Ks[nt*16 + l16][quad*8];
            bf16x8 kb1 = *(const bf16x8*)&Ks[nt*16 + l16][32 + quad*8];
            sacc[nt] = __builtin_amdgcn_mfma_f32_16x16x32_bf16(qa0, kb0, sacc[nt], 0, 0, 0);
            sacc[nt] = __builtin_amdgcn_mfma_f32_16x16x32_bf16(qa1, kb1, sacc[nt], 0, 0, 0);
        }
        #pragma unroll
        for (int r = 0; r < 4; ++r) {
            float sv0 = sacc[0][r]*0.125f, sv1 = sacc[1][r]*0.125f;
            float sv2 = sacc[2][r]*0.125f, sv3 = sacc[3][r]*0.125f;
            float mx = fmaxf(fmaxf(sv0, sv1), fmaxf(sv2, sv3));
            #pragma unroll
            for (int o = 1; o < 16; o <<= 1) mx = fmaxf(mx, __shfl_xor(mx, o));
            float mnew = fmaxf(mst[r], mx);
            float alpha = __expf(mst[r] - mnew);
            float p0 = __expf(sv0 - mnew), p1 = __expf(sv1 - mnew);
            float p2 = __expf(sv2 - mnew), p3 = __expf(sv3 - mnew);
            float ls = p0 + p1 + p2 + p3;
            #pragma unroll
            for (int o = 1; o < 16; o <<= 1) ls += __shfl_xor(ls, o);
            lst[r] = lst[r]*alpha + ls;
            mst[r] = mnew;
            #pragma unroll
            for (int dt = 0; dt < 4; ++dt) oacc[dt][r] *= alpha;
            int qr = quad*4 + r;
            Ps[w][qr][ 0 + l16] = fb(p0);
            Ps[w][qr][16 + l16] = fb(p1);
            Ps[w][qr][32 + l16] = fb(p2);
            Ps[w][qr][48 + l16] = fb(p3);
        }
        bf16x8 pa0 = *(const bf16x8*)&Ps[w][l16][quad*8];
        bf16x8 pa1 = *(const bf16x8*)&Ps[w][l16][32 + quad*8];
        #pragma unroll
        for (int dt = 0; dt < 4; ++dt) {
            bf16x8 vb0 = *(const bf16x8*)&Vs[dt*16 + l16][quad*8];
            bf16x8 vb1 = *(const bf16x8*)&Vs[dt*16 + l16][32 + quad*8];
            oacc[dt] = __builtin_amdgcn_mfma_f32_16x16x32_bf16(pa0, vb0, oacc[dt], 0, 0, 0);
            oacc[dt] = __builtin_amdgcn_mfma_f32_16x16x32_bf16(pa1, vb1, oacc[dt], 0, 0, 0);
        }
    }
    #pragma unroll
    for (int dt = 0; dt < 4; ++dt)
        #pragma unroll
        for (int r = 0; r < 4; ++r)
            attn_out[(size_t)(qrow0 + quad*4 + r)*DD + head*64 + dt*16 + l16] = fb(oacc[dt][r] / lst[r]);
}

extern "C" void kernel_launch(void* const* d_in, const int* in_sizes, int n_in,
                              void* d_out, int out_size, void* d_ws, size_t ws_size,
                              hipStream_t stream) {
    const float* x          = (const float*)d_in[0];
    const float* c          = (const float*)d_in[1];
    const float* attn_qkv_w = (const float*)d_in[2];
    const float* attn_qkv_b = (const float*)d_in[3];
    const float* attn_proj_w= (const float*)d_in[4];
    const float* attn_proj_b= (const float*)d_in[5];
    const float* crs_qkv_w  = (const float*)d_in[6];
    const float* crs_qkv_b  = (const float*)d_in[7];
    const float* crs_proj_w = (const float*)d_in[8];
    const float* crs_proj_b = (const float*)d_in[9];
    const float* fc1_w      = (const float*)d_in[10];
    const float* fc1_b      = (const float*)d_in[11];
    const float* fc2_w      = (const float*)d_in[12];
    const float* fc2_b      = (const float*)d_in[13];
    const float* ada_w      = (const float*)d_in[14];
    const float* ada_b      = (const float*)d_in[15];
    float* out = (float*)d_out;     // f32 running residual (= x; MSA branch excluded per reference)

    // ws: mod 0.25 MB | R1 16 MB | Yr 8 MB | AOr 8 MB | BIGr 24 MB = 56.25 MB
    char* ws = (char*)d_ws;
    float* mod = (float*)ws;
    char* R1   = ws + (256u<<10);
    char* Yr   = R1 + (16u<<20);
    char* AOr  = Yr + (8u<<20);
    char* BIGr = AOr + (8u<<20);

    float* x0x1  = (float*)R1;                 // 16 MB (MSA resid-add -> MCA ln)
    u16*   wt_a  = (u16*)R1;                   // 6 MB qkv weight T (dead before x0x1)
    u16*   vt    = (u16*)(R1 + (8u<<20));      // 8 MB V-transpose
    bf16*  y     = (bf16*)Yr;                  // 8 MB ln output
    u16*   wt_p  = (u16*)Yr;                   // 2 MB proj weight T (y dead)
    u16*   attn_o= (u16*)AOr;                  // 8 MB
    u16*   big   = (u16*)BIGr;                 // 24 MB qkv
    u16*   gvB   = (u16*)BIGr;                 // 8 MB gated branch output (big dead)
    u16*   gvY   = (u16*)Yr;                   // 8 MB gated fc2 output (y dead)
    u16*   hstage= (u16*)AOr;                  // 32 MB fc1 out (AOr+BIGr contiguous; attn_o/big dead)
    u16*   fc1_t = (u16*)R1;                   // 8 MB
    u16*   fc2_t = (u16*)(R1 + (8u<<20));      // 8 MB
    float* apart = (float*)BIGr;               // 2.4 MB ada partials (pre-MSA only)

    ada_part<<<dim3(9, 16), 256, 0, stream>>>(c, ada_w, apart);
    ada_reduce<<<36, 256, 0, stream>>>(apart, ada_b, mod);
    cast_x4<<<4096, 256, 0, stream>>>(x, out);

    // ================= MSA =================
    transpose_w<<<dim3(3*DD/32, DD/32), 256, 0, stream>>>(attn_qkv_w, wt_a, DD, 3*DD);
    ln_mod_kernel<<<ROWS, 256, 0, stream>>>(out, mod, 0, 1, y);
    gemm_mfma<<<dim3(3*DD/128, ROWS/128), 256, 0, stream>>>((const u16*)y, wt_a, attn_qkv_b,
                                                            big, nullptr, 0, 0, 0, 0, DD, 3*DD, 0);
    vtrans<<<dim3(16, 64), 256, 0, stream>>>(big, vt);
    attn_mfma<<<dim3(16, NH, 4), 256, 0, stream>>>(big, vt, attn_o, 0);
    transpose_w<<<dim3(DD/32, DD/32), 256, 0, stream>>>(attn_proj_w, wt_p, DD, DD);
    gemm64<<<dim3(DD/128, ROWS/64), 256, 0, stream>>>(attn_o, wt_p, attn_proj_b,
                                                      gvB, mod, 2, 0, 0, 0, DD, DD, 3);
    resid_add<<<4096, 256, 0, stream>>>(out, gvB, x0x1);

    // ================= MCA =================
    ln_mod_kernel<<<ROWS, 256, 0, stream>>>(x0x1, mod, 3, 4, y);   // consume x0x1 before R1 reuse
    transpose_w<<<dim3(3*DD/32, DD/32), 256, 0, stream>>>(crs_qkv_w, wt_a, DD, 3*DD);
    gemm_mfma<<<dim3(3*DD/128, ROWS/128), 256, 0, stream>>>((const u16*)y, wt_a, crs_qkv_b,
                                                            big, nullptr, 0, 0, 0, 0, DD, 3*DD, 0);
    vtrans<<<dim3(16, 64), 256, 0, stream>>>(big, vt);
    attn_mfma<<<dim3(16, NH, 4), 256, 0, stream>>>(big, vt, attn_o, 1);
    transpose_w<<<dim3(DD/32, DD/32), 256, 0, stream>>>(crs_proj_w, wt_p, DD, DD);
    gemm64<<<dim3(DD/128, ROWS/64), 256, 0, stream>>>(attn_o, wt_p, crs_proj_b,
                                                      gvB, mod, 5, 0, 0, 0, DD, DD, 3);
    resid_add<<<4096, 256, 0, stream>>>(out, gvB, out);

    // ================= MLP =================
    ln_mod_kernel<<<ROWS, 256, 0, stream>>>(out, mod, 6, 7, y);
    transpose_w<<<dim3(DHID/32, DD/32), 256, 0, stream>>>(fc1_w, fc1_t, DD, DHID);
    transpose_w<<<dim3(DD/32, DHID/32), 256, 0, stream>>>(fc2_w, fc2_t, DHID, DD);
    gemm_mfma<<<dim3(DHID/128, ROWS/128), 256, 0, stream>>>((const u16*)y, fc1_t, fc1_b,
                                                            hstage, nullptr, 0, 0, 0, 0, DD, DHID, 1);
    gemm64<<<dim3(DD/128, ROWS/64), 256, 0, stream>>>(hstage, fc2_t, fc2_b,
                                                      gvY, mod, 8, 0, 0, 0, DHID, DD, 3);
    resid_add<<<4096, 256, 0, stream>>>(out, gvY, out);
}

// Round 9
// 609.731 us; speedup vs baseline: 13.6424x; 1.0296x over previous
//
#include <hip/hip_runtime.h>
#include <hip/hip_bf16.h>

#define BB 2
#define TT 2048
#define DD 1024
#define NH 16
#define HALF 1024
#define DHID 4096
#define ND9 9216
#define ROWS (BB*TT)

using bf16 = __hip_bfloat16;
typedef short bf16x8 __attribute__((ext_vector_type(8)));
typedef float f32x4 __attribute__((ext_vector_type(4)));
typedef unsigned short u16;

__device__ __forceinline__ float b2f(bf16 v){ return __bfloat162float(v); }
__device__ __forceinline__ bf16 f2b(float v){ return __float2bfloat16(v); }
__device__ __forceinline__ float bits2f(u16 b){ return __uint_as_float(((unsigned)b) << 16); }
__device__ __forceinline__ u16 fb(float v){              // float -> bf16 bits (RNE)
    unsigned u = __float_as_uint(v);
    u += 0x7fffu + ((u >> 16) & 1u);
    return (u16)(u >> 16);
}
__device__ __forceinline__ void gl_lds16(const u16* g, u16* l) {
    __builtin_amdgcn_global_load_lds(
        (const __attribute__((address_space(1))) unsigned int*)g,
        (__attribute__((address_space(3))) unsigned int*)l, 16, 0, 0);
}

// ---------------- ada stage 1: partial[s][r][n] over 64-k slices ----------------
__global__ void ada_part(const float* __restrict__ c, const float* __restrict__ ada_w,
                         float* __restrict__ part) {
    __shared__ float sc_[4][64];
    int s = blockIdx.y;
    int k0 = s * 64;
    int n0 = blockIdx.x * 1024 + threadIdx.x * 4;
    {
        int r = threadIdx.x >> 6, k = threadIdx.x & 63;
        float v = c[r*DD + k0 + k];
        sc_[r][k] = v / (1.f + __expf(-v));
    }
    __syncthreads();
    float4 a0 = {0,0,0,0}, a1 = {0,0,0,0}, a2 = {0,0,0,0}, a3 = {0,0,0,0};
    for (int k = 0; k < 64; ++k) {
        float4 wv = *(const float4*)&ada_w[(size_t)(k0 + k)*ND9 + n0];
        float s0 = sc_[0][k], s1 = sc_[1][k], s2 = sc_[2][k], s3 = sc_[3][k];
        a0.x += s0*wv.x; a0.y += s0*wv.y; a0.z += s0*wv.z; a0.w += s0*wv.w;
        a1.x += s1*wv.x; a1.y += s1*wv.y; a1.z += s1*wv.z; a1.w += s1*wv.w;
        a2.x += s2*wv.x; a2.y += s2*wv.y; a2.z += s2*wv.z; a2.w += s2*wv.w;
        a3.x += s3*wv.x; a3.y += s3*wv.y; a3.z += s3*wv.z; a3.w += s3*wv.w;
    }
    *(float4*)&part[((size_t)(s*4 + 0))*ND9 + n0] = a0;
    *(float4*)&part[((size_t)(s*4 + 1))*ND9 + n0] = a1;
    *(float4*)&part[((size_t)(s*4 + 2))*ND9 + n0] = a2;
    *(float4*)&part[((size_t)(s*4 + 3))*ND9 + n0] = a3;
}

// ---------------- ada stage 2 ----------------
__global__ void ada_reduce(const float* __restrict__ part, const float* __restrict__ ada_b,
                           float* __restrict__ mod) {
    int g = blockIdx.x * 1024 + threadIdx.x * 4;
    int r = g / ND9, n = g - r*ND9;
    float4 acc = *(const float4*)&ada_b[n];
    #pragma unroll
    for (int s = 0; s < 16; ++s) {
        float4 p = *(const float4*)&part[((size_t)(s*4 + r))*ND9 + n];
        acc.x += p.x; acc.y += p.y; acc.z += p.z; acc.w += p.w;
    }
    *(float4*)&mod[(size_t)r*ND9 + n] = acc;
}

// ---------------- resid(out) = copy(x), float4 ----------------
__global__ void cast_x4(const float* __restrict__ x, float* __restrict__ xc) {
    int i = (blockIdx.x * 256 + threadIdx.x) * 4;
    *(float4*)&xc[i] = *(const float4*)&x[i];
}

// ---------------- dst = src + bf16(gv), float4 ----------------
__global__ void resid_add(const float* __restrict__ src, const u16* __restrict__ gv,
                          float* __restrict__ dst) {
    int i = (blockIdx.x * 256 + threadIdx.x) * 4;
    float4 s = *(const float4*)&src[i];
    ushort4 g = *(const ushort4*)&gv[i];
    float4 o;
    o.x = s.x + bits2f(g.x); o.y = s.y + bits2f(g.y);
    o.z = s.z + bits2f(g.z); o.w = s.w + bits2f(g.w);
    *(float4*)&dst[i] = o;
}

// ---------------- fused: xn = src (+ gv); [dstf = xn]; y = mod(ln(xn)) ----------------
__global__ void resid_ln(const float* __restrict__ src, const u16* __restrict__ gv,
                         const float* __restrict__ mod, int jshift, int jscale,
                         float* __restrict__ dstf, bf16* __restrict__ y) {
    int row = blockIdx.x;
    int b = row / TT, t = row % TT;
    int cz = (t >= HALF) ? 1 : 0;
    const float* mp = mod + (size_t)(b*2 + cz) * ND9;
    int tid = threadIdx.x;
    int d0 = tid * 4;
    float4 s = *(const float4*)&src[(size_t)row*DD + d0];
    float v[4] = {s.x, s.y, s.z, s.w};
    if (gv) {
        ushort4 g = *(const ushort4*)&gv[(size_t)row*DD + d0];
        v[0] += bits2f(g.x); v[1] += bits2f(g.y); v[2] += bits2f(g.z); v[3] += bits2f(g.w);
    }
    if (dstf) *(float4*)&dstf[(size_t)row*DD + d0] = (float4){v[0], v[1], v[2], v[3]};
    float sum = v[0]+v[1]+v[2]+v[3];
    float ssq = v[0]*v[0]+v[1]*v[1]+v[2]*v[2]+v[3]*v[3];
    __shared__ float red[256];
    red[tid] = sum; __syncthreads();
    for (int o = 128; o > 0; o >>= 1) { if (tid < o) red[tid] += red[tid+o]; __syncthreads(); }
    float mean = red[0] * (1.f/DD);
    __syncthreads();
    red[tid] = ssq; __syncthreads();
    for (int o = 128; o > 0; o >>= 1) { if (tid < o) red[tid] += red[tid+o]; __syncthreads(); }
    float var = red[0] * (1.f/DD) - mean*mean;
    float rstd = rsqrtf(var + 1e-6f);
    float4 sh = *(const float4*)&mp[jshift*DD + d0];
    float4 sc = *(const float4*)&mp[jscale*DD + d0];
    ushort4 o4;
    o4.x = fb((v[0]-mean)*rstd*(1.f+sc.x) + sh.x);
    o4.y = fb((v[1]-mean)*rstd*(1.f+sc.y) + sh.y);
    o4.z = fb((v[2]-mean)*rstd*(1.f+sc.z) + sh.z);
    o4.w = fb((v[3]-mean)*rstd*(1.f+sc.w) + sh.w);
    *(ushort4*)((u16*)y + (size_t)row*DD + d0) = o4;
}

// ---------------- W (KxN f32) -> Wt (NxK bf16 bits) ----------------
__global__ void transpose_w(const float* __restrict__ W, u16* __restrict__ Wt, int K, int N) {
    __shared__ float T[32][33];
    int n0 = blockIdx.x * 32, k0 = blockIdx.y * 32;
    int lx = threadIdx.x & 31, ly = threadIdx.x >> 5;
    #pragma unroll
    for (int i = 0; i < 4; ++i)
        T[ly + i*8][lx] = W[(size_t)(k0 + ly + i*8)*N + n0 + lx];
    __syncthreads();
    #pragma unroll
    for (int i = 0; i < 4; ++i) {
        int n = ly + i*8;
        Wt[(size_t)(n0 + n)*K + k0 + lx] = fb(T[lx][n]);
    }
}

// ---------------- V slice of qkv -> vt[bh*16+head][d][key] ----------------
__global__ void vtrans(const u16* __restrict__ qkv, u16* __restrict__ vt) {
    __shared__ u16 T[64][72];
    int kt = blockIdx.x;
    int gh = blockIdx.y;
    int tid = threadIdx.x;
    int key = tid >> 2, c8 = (tid & 3) * 16;
    const u16* src = qkv + (size_t)((gh >> 4)*1024 + kt*64 + key)*3072 + 2048 + (gh & 15)*64 + c8;
    *(uint4*)&T[key][c8]     = *(const uint4*)src;
    *(uint4*)&T[key][c8 + 8] = *(const uint4*)(src + 8);
    __syncthreads();
    int d = tid >> 2, kc = (tid & 3) * 16;
    u16 tmp[16];
    #pragma unroll
    for (int i = 0; i < 16; ++i) tmp[i] = T[kc + i][d];
    u16* dst = vt + ((size_t)gh*64 + d)*1024 + kt*64 + kc;
    *(uint4*)&dst[0] = *(const uint4*)&tmp[0];
    *(uint4*)&dst[8] = *(const uint4*)&tmp[8];
}

// ---------------- epilogue helper ----------------
__device__ __forceinline__ void epi_store(u16* out, int o_off, int N, int mm, int n, float v,
                                          const float* mod, int jg, int epi) {
    if (epi == 0) {
        out[(size_t)(mm - o_off)*N + n] = fb(v);
    } else if (epi == 1) {
        float z = 0.7978845608028654f*(v + 0.044715f*v*v*v);
        out[(size_t)(mm - o_off)*N + n] = fb(v / (1.f + __expf(-2.f*z)));
    } else {
        int brow = mm / TT, tt2 = mm % TT;
        int cz = (tt2 >= HALF) ? 1 : 0;
        const float* mp = mod + (size_t)(brow*2 + cz)*ND9 + (size_t)jg*DD;
        out[(size_t)(mm - o_off)*N + n] = fb(mp[n]*v);
    }
}

// ---------------- MFMA GEMM 128x128 tile, BK=64, swizzled LDS ----------------
__global__ __launch_bounds__(256, 2) void gemm_mfma(
    const u16* __restrict__ A, const u16* __restrict__ Wt, const float* __restrict__ bias,
    u16* __restrict__ out, const float* __restrict__ mod, int jg,
    int m_base, int a_off, int o_off, int K, int N, int epi)
{
    __shared__ u16 As[128*64];
    __shared__ u16 Bs[128*64];
    int tid = threadIdx.x;
    int w = tid >> 6, lane = tid & 63;
    int quad = lane >> 4, l16 = lane & 15;
    int m0 = m_base + blockIdx.y * 128;
    int n0 = blockIdx.x * 128;
    int wr = (w & 1) * 64, wc = (w >> 1) * 64;

    f32x4 acc[4][4];
    #pragma unroll
    for (int i = 0; i < 4; ++i)
        #pragma unroll
        for (int j = 0; j < 4; ++j) acc[i][j] = (f32x4){0.f,0.f,0.f,0.f};

    const u16* Ag = A + (size_t)(m0 - a_off) * K;
    const u16* Bg = Wt + (size_t)n0 * K;
    int srow = lane >> 3;                                  // 0..7 (8 rows/chunk)
    int scol = (((lane & 7) ^ ((lane >> 3) & 7))) * 8;     // XOR swizzle on writer
    int xsw = (l16 & 7);                                   // reader row-swizzle key

    for (int k0 = 0; k0 < K; k0 += 64) {
        #pragma unroll
        for (int c = 0; c < 4; ++c) {
            int ch = w*4 + c;                              // 16 chunks of 8 rows
            gl_lds16(Ag + (size_t)(ch*8 + srow)*K + k0 + scol, As + ch*512);
            gl_lds16(Bg + (size_t)(ch*8 + srow)*K + k0 + scol, Bs + ch*512);
        }
        __syncthreads();
        #pragma unroll
        for (int kk = 0; kk < 2; ++kk) {
            int pc = ((kk*4 + quad) ^ xsw) * 8;
            bf16x8 af[4], bfr[4];
            #pragma unroll
            for (int i = 0; i < 4; ++i) af[i] = *(const bf16x8*)&As[(wr + i*16 + l16)*64 + pc];
            #pragma unroll
            for (int j = 0; j < 4; ++j) bfr[j] = *(const bf16x8*)&Bs[(wc + j*16 + l16)*64 + pc];
            #pragma unroll
            for (int i = 0; i < 4; ++i)
                #pragma unroll
                for (int j = 0; j < 4; ++j)
                    acc[i][j] = __builtin_amdgcn_mfma_f32_16x16x32_bf16(af[i], bfr[j], acc[i][j], 0, 0, 0);
        }
        __syncthreads();
    }

    #pragma unroll
    for (int i = 0; i < 4; ++i)
        #pragma unroll
        for (int r = 0; r < 4; ++r) {
            int mm = m0 + wr + i*16 + quad*4 + r;
            #pragma unroll
            for (int j = 0; j < 4; ++j) {
                int n = n0 + wc + j*16 + l16;
                epi_store(out, o_off, N, mm, n, acc[i][j][r] + bias[n], mod, jg, epi);
            }
        }
}

// ---------------- MFMA GEMM 64x128 tile (narrow-N), BK=64, swizzled ----------------
__global__ __launch_bounds__(256, 2) void gemm64(
    const u16* __restrict__ A, const u16* __restrict__ Wt, const float* __restrict__ bias,
    u16* __restrict__ out, const float* __restrict__ mod, int jg,
    int m_base, int a_off, int o_off, int K, int N, int epi)
{
    __shared__ u16 As[64*64];
    __shared__ u16 Bs[128*64];
    int tid = threadIdx.x;
    int w = tid >> 6, lane = tid & 63;
    int quad = lane >> 4, l16 = lane & 15;
    int m0 = m_base + blockIdx.y * 64;
    int n0 = blockIdx.x * 128;

    f32x4 acc[4][2];
    #pragma unroll
    for (int i = 0; i < 4; ++i)
        #pragma unroll
        for (int j = 0; j < 2; ++j) acc[i][j] = (f32x4){0.f,0.f,0.f,0.f};

    const u16* Ag = A + (size_t)(m0 - a_off) * K;
    const u16* Bg = Wt + (size_t)n0 * K;
    int srow = lane >> 3;
    int scol = (((lane & 7) ^ ((lane >> 3) & 7))) * 8;
    int xsw = (l16 & 7);

    for (int k0 = 0; k0 < K; k0 += 64) {
        #pragma unroll
        for (int c = 0; c < 2; ++c) {
            int ch = w*2 + c;                              // A: 8 chunks
            gl_lds16(Ag + (size_t)(ch*8 + srow)*K + k0 + scol, As + ch*512);
        }
        #pragma unroll
        for (int c = 0; c < 4; ++c) {
            int ch = w*4 + c;                              // B: 16 chunks
            gl_lds16(Bg + (size_t)(ch*8 + srow)*K + k0 + scol, Bs + ch*512);
        }
        __syncthreads();
        #pragma unroll
        for (int kk = 0; kk < 2; ++kk) {
            int pc = ((kk*4 + quad) ^ xsw) * 8;
            bf16x8 af[4], bfr[2];
            #pragma unroll
            for (int i = 0; i < 4; ++i) af[i] = *(const bf16x8*)&As[(i*16 + l16)*64 + pc];
            #pragma unroll
            for (int j = 0; j < 2; ++j) bfr[j] = *(const bf16x8*)&Bs[(w*32 + j*16 + l16)*64 + pc];
            #pragma unroll
            for (int i = 0; i < 4; ++i)
                #pragma unroll
                for (int j = 0; j < 2; ++j)
                    acc[i][j] = __builtin_amdgcn_mfma_f32_16x16x32_bf16(af[i], bfr[j], acc[i][j], 0, 0, 0);
        }
        __syncthreads();
    }

    #pragma unroll
    for (int i = 0; i < 4; ++i)
        #pragma unroll
        for (int r = 0; r < 4; ++r) {
            int mm = m0 + i*16 + quad*4 + r;
            #pragma unroll
            for (int j = 0; j < 2; ++j) {
                int n = n0 + w*32 + j*16 + l16;
                epi_store(out, o_off, N, mm, n, acc[i][j][r] + bias[n], mod, jg, epi);
            }
        }
}

// ---------------- MFMA flash attention, both batches in one dispatch ----------------
__global__ __launch_bounds__(256) void attn_mfma(const u16* __restrict__ qkv,
                                                 const u16* __restrict__ vt,
                                                 u16* __restrict__ attn_out, int kv_swap) {
    __shared__ u16 Ks[64][72];
    __shared__ u16 Vs[64][72];
    __shared__ u16 Ps[4][16][72];
    int qt = blockIdx.x, head = blockIdx.y, bh = blockIdx.z;
    int kvbh = kv_swap ? (bh ^ 1) : bh;
    int tid = threadIdx.x;
    int w = tid >> 6, lane = tid & 63;
    int quad = lane >> 4, l16 = lane & 15;
    int qrow0 = bh*1024 + qt*64 + w*16;

    const u16* qp = qkv + (size_t)(qrow0 + l16)*3072 + head*64;
    bf16x8 qa0 = *(const bf16x8*)(qp + quad*8);
    bf16x8 qa1 = *(const bf16x8*)(qp + 32 + quad*8);

    f32x4 oacc[4];
    #pragma unroll
    for (int i = 0; i < 4; ++i) oacc[i] = (f32x4){0.f,0.f,0.f,0.f};
    float mst[4], lst[4];
    #pragma unroll
    for (int r = 0; r < 4; ++r) { mst[r] = -3e38f; lst[r] = 0.f; }

    int skey = tid >> 2, sc8 = (tid & 3) * 16;
    const u16* kbase = qkv + (size_t)(kvbh*1024 + skey)*3072 + 1024 + head*64 + sc8;
    const u16* vbase = vt + ((size_t)(kvbh*16 + head)*64 + skey)*1024 + sc8;

    for (int kt = 0; kt < 16; ++kt) {
        __syncthreads();
        const u16* kp = kbase + (size_t)kt*64*3072;
        *(uint4*)&Ks[skey][sc8]     = *(const uint4*)kp;
        *(uint4*)&Ks[skey][sc8 + 8] = *(const uint4*)(kp + 8);
        const u16* vp = vbase + kt*64;
        *(uint4*)&Vs[skey][sc8]     = *(const uint4*)vp;
        *(uint4*)&Vs[skey][sc8 + 8] = *(const uint4*)(vp + 8);
        __syncthreads();

        f32x4 sacc[4];
        #pragma unroll
        for (int nt = 0; nt < 4; ++nt) sacc[nt] = (f32x4){0.f,0.f,0.f,0.f};
        #pragma unroll
        for (int nt = 0; nt < 4; ++nt) {
            bf16x8 kb0 = *(const bf16x8*)&Ks[nt*16 + l16][quad*8];
            bf16x8 kb1 = *(const bf16x8*)&Ks[nt*16 + l16][32 + quad*8];
            sacc[nt] = __builtin_amdgcn_mfma_f32_16x16x32_bf16(qa0, kb0, sacc[nt], 0, 0, 0);
            sacc[nt] = __builtin_amdgcn_mfma_f32_16x16x32_bf16(qa1, kb1, sacc[nt], 0, 0, 0);
        }
        #pragma unroll
        for (int r = 0; r < 4; ++r) {
            float sv0 = sacc[0][r]*0.125f, sv1 = sacc[1][r]*0.125f;
            float sv2 = sacc[2][r]*0.125f, sv3 = sacc[3][r]*0.125f;
            float mx = fmaxf(fmaxf(sv0, sv1), fmaxf(sv2, sv3));
            #pragma unroll
            for (int o = 1; o < 16; o <<= 1) mx = fmaxf(mx, __shfl_xor(mx, o));
            float mnew = fmaxf(mst[r], mx);
            float alpha = __expf(mst[r] - mnew);
            float p0 = __expf(sv0 - mnew), p1 = __expf(sv1 - mnew);
            float p2 = __expf(sv2 - mnew), p3 = __expf(sv3 - mnew);
            float ls = p0 + p1 + p2 + p3;
            #pragma unroll
            for (int o = 1; o < 16; o <<= 1) ls += __shfl_xor(ls, o);
            lst[r] = lst[r]*alpha + ls;
            mst[r] = mnew;
            #pragma unroll
            for (int dt = 0; dt < 4; ++dt) oacc[dt][r] *= alpha;
            int qr = quad*4 + r;
            Ps[w][qr][ 0 + l16] = fb(p0);
            Ps[w][qr][16 + l16] = fb(p1);
            Ps[w][qr][32 + l16] = fb(p2);
            Ps[w][qr][48 + l16] = fb(p3);
        }
        bf16x8 pa0 = *(const bf16x8*)&Ps[w][l16][quad*8];
        bf16x8 pa1 = *(const bf16x8*)&Ps[w][l16][32 + quad*8];
        #pragma unroll
        for (int dt = 0; dt < 4; ++dt) {
            bf16x8 vb0 = *(const bf16x8*)&Vs[dt*16 + l16][quad*8];
            bf16x8 vb1 = *(const bf16x8*)&Vs[dt*16 + l16][32 + quad*8];
            oacc[dt] = __builtin_amdgcn_mfma_f32_16x16x32_bf16(pa0, vb0, oacc[dt], 0, 0, 0);
            oacc[dt] = __builtin_amdgcn_mfma_f32_16x16x32_bf16(pa1, vb1, oacc[dt], 0, 0, 0);
        }
    }
    #pragma unroll
    for (int dt = 0; dt < 4; ++dt)
        #pragma unroll
        for (int r = 0; r < 4; ++r)
            attn_out[(size_t)(qrow0 + quad*4 + r)*DD + head*64 + dt*16 + l16] = fb(oacc[dt][r] / lst[r]);
}

extern "C" void kernel_launch(void* const* d_in, const int* in_sizes, int n_in,
                              void* d_out, int out_size, void* d_ws, size_t ws_size,
                              hipStream_t stream) {
    const float* x          = (const float*)d_in[0];
    const float* c          = (const float*)d_in[1];
    const float* attn_qkv_w = (const float*)d_in[2];
    const float* attn_qkv_b = (const float*)d_in[3];
    const float* attn_proj_w= (const float*)d_in[4];
    const float* attn_proj_b= (const float*)d_in[5];
    const float* crs_qkv_w  = (const float*)d_in[6];
    const float* crs_qkv_b  = (const float*)d_in[7];
    const float* crs_proj_w = (const float*)d_in[8];
    const float* crs_proj_b = (const float*)d_in[9];
    const float* fc1_w      = (const float*)d_in[10];
    const float* fc1_b      = (const float*)d_in[11];
    const float* fc2_w      = (const float*)d_in[12];
    const float* fc2_b      = (const float*)d_in[13];
    const float* ada_w      = (const float*)d_in[14];
    const float* ada_b      = (const float*)d_in[15];
    float* out = (float*)d_out;     // f32 running residual (= x; MSA branch excluded per reference)

    // ws: mod 0.25 MB | R1 16 MB | Yr 8 MB | AOr 8 MB | BIGr 24 MB = 56.25 MB
    char* ws = (char*)d_ws;
    float* mod = (float*)ws;
    char* R1   = ws + (256u<<10);
    char* Yr   = R1 + (16u<<20);
    char* AOr  = Yr + (8u<<20);
    char* BIGr = AOr + (8u<<20);

    u16*   wt_a  = (u16*)R1;                   // 6 MB qkv weight T
    u16*   vt    = (u16*)(R1 + (8u<<20));      // 8 MB V-transpose
    bf16*  y     = (bf16*)Yr;                  // 8 MB ln output
    u16*   wt_p  = (u16*)Yr;                   // 2 MB proj weight T (y dead)
    u16*   attn_o= (u16*)AOr;                  // 8 MB
    u16*   big   = (u16*)BIGr;                 // 24 MB qkv
    u16*   gvB   = (u16*)BIGr;                 // 8 MB gated branch output (big dead)
    u16*   gvY   = (u16*)Yr;                   // 8 MB gated fc2 output (y dead)
    u16*   hstage= (u16*)AOr;                  // 32 MB fc1 out (AOr+BIGr contiguous)
    u16*   fc1_t = (u16*)R1;                   // 8 MB
    u16*   fc2_t = (u16*)(R1 + (8u<<20));      // 8 MB
    float* apart = (float*)BIGr;               // 2.4 MB ada partials (pre-MSA only)

    ada_part<<<dim3(9, 16), 256, 0, stream>>>(c, ada_w, apart);
    ada_reduce<<<36, 256, 0, stream>>>(apart, ada_b, mod);
    cast_x4<<<4096, 256, 0, stream>>>(x, out);

    // ================= MSA =================
    transpose_w<<<dim3(3*DD/32, DD/32), 256, 0, stream>>>(attn_qkv_w, wt_a, DD, 3*DD);
    resid_ln<<<ROWS, 256, 0, stream>>>(out, nullptr, mod, 0, 1, nullptr, y);
    gemm_mfma<<<dim3(3*DD/128, ROWS/128), 256, 0, stream>>>((const u16*)y, wt_a, attn_qkv_b,
                                                            big, nullptr, 0, 0, 0, 0, DD, 3*DD, 0);
    vtrans<<<dim3(16, 64), 256, 0, stream>>>(big, vt);
    attn_mfma<<<dim3(16, NH, 4), 256, 0, stream>>>(big, vt, attn_o, 0);
    transpose_w<<<dim3(DD/32, DD/32), 256, 0, stream>>>(attn_proj_w, wt_p, DD, DD);
    gemm64<<<dim3(DD/128, ROWS/64), 256, 0, stream>>>(attn_o, wt_p, attn_proj_b,
                                                      gvB, mod, 2, 0, 0, 0, DD, DD, 3);
    // y = mod(ln(out + gvB)) for MCA; running residual (out) unchanged per reference
    resid_ln<<<ROWS, 256, 0, stream>>>(out, gvB, mod, 3, 4, nullptr, y);

    // ================= MCA =================
    transpose_w<<<dim3(3*DD/32, DD/32), 256, 0, stream>>>(crs_qkv_w, wt_a, DD, 3*DD);
    gemm_mfma<<<dim3(3*DD/128, ROWS/128), 256, 0, stream>>>((const u16*)y, wt_a, crs_qkv_b,
                                                            big, nullptr, 0, 0, 0, 0, DD, 3*DD, 0);
    vtrans<<<dim3(16, 64), 256, 0, stream>>>(big, vt);
    attn_mfma<<<dim3(16, NH, 4), 256, 0, stream>>>(big, vt, attn_o, 1);
    transpose_w<<<dim3(DD/32, DD/32), 256, 0, stream>>>(crs_proj_w, wt_p, DD, DD);
    gemm64<<<dim3(DD/128, ROWS/64), 256, 0, stream>>>(attn_o, wt_p, crs_proj_b,
                                                      gvB, mod, 5, 0, 0, 0, DD, DD, 3);
    // out += gvB (store), y = mod(ln(out)) for MLP
    resid_ln<<<ROWS, 256, 0, stream>>>(out, gvB, mod, 6, 7, out, y);

    // ================= MLP =================
    transpose_w<<<dim3(DHID/32, DD/32), 256, 0, stream>>>(fc1_w, fc1_t, DD, DHID);
    transpose_w<<<dim3(DD/32, DHID/32), 256, 0, stream>>>(fc2_w, fc2_t, DHID, DD);
    gemm_mfma<<<dim3(DHID/128, ROWS/128), 256, 0, stream>>>((const u16*)y, fc1_t, fc1_b,
                                                            hstage, nullptr, 0, 0, 0, 0, DD, DHID, 1);
    gemm64<<<dim3(DD/128, ROWS/64), 256, 0, stream>>>(hstage, fc2_t, fc2_b,
                                                      gvY, mod, 8, 0, 0, 0, DHID, DD, 3);
    resid_add<<<4096, 256, 0, stream>>>(out, gvY, out);
}

// Round 10
// 535.453 us; speedup vs baseline: 15.5349x; 1.1387x over previous
//
#include <hip/hip_runtime.h>
#include <hip/hip_bf16.h>

#define BB 2
#define TT 2048
#define DD 1024
#define NH 16
#define HALF 1024
#define DHID 4096
#define ND9 9216
#define ROWS (BB*TT)

using bf16 = __hip_bfloat16;
typedef short bf16x8 __attribute__((ext_vector_type(8)));
typedef float f32x4 __attribute__((ext_vector_type(4)));
typedef unsigned short u16;

__device__ __forceinline__ float b2f(bf16 v){ return __bfloat162float(v); }
__device__ __forceinline__ bf16 f2b(float v){ return __float2bfloat16(v); }
__device__ __forceinline__ float bits2f(u16 b){ return __uint_as_float(((unsigned)b) << 16); }
__device__ __forceinline__ u16 fb(float v){              // float -> bf16 bits (RNE)
    unsigned u = __float_as_uint(v);
    u += 0x7fffu + ((u >> 16) & 1u);
    return (u16)(u >> 16);
}
__device__ __forceinline__ void gl_lds16(const u16* g, u16* l) {
    __builtin_amdgcn_global_load_lds(
        (const __attribute__((address_space(1))) unsigned int*)g,
        (__attribute__((address_space(3))) unsigned int*)l, 16, 0, 0);
}

// ---------------- ada stage 1: partial[s][r][n] over 64-k slices ----------------
__global__ void ada_part(const float* __restrict__ c, const float* __restrict__ ada_w,
                         float* __restrict__ part) {
    __shared__ float sc_[4][64];
    int s = blockIdx.y;
    int k0 = s * 64;
    int n0 = blockIdx.x * 1024 + threadIdx.x * 4;
    {
        int r = threadIdx.x >> 6, k = threadIdx.x & 63;
        float v = c[r*DD + k0 + k];
        sc_[r][k] = v / (1.f + __expf(-v));
    }
    __syncthreads();
    float4 a0 = {0,0,0,0}, a1 = {0,0,0,0}, a2 = {0,0,0,0}, a3 = {0,0,0,0};
    for (int k = 0; k < 64; ++k) {
        float4 wv = *(const float4*)&ada_w[(size_t)(k0 + k)*ND9 + n0];
        float s0 = sc_[0][k], s1 = sc_[1][k], s2 = sc_[2][k], s3 = sc_[3][k];
        a0.x += s0*wv.x; a0.y += s0*wv.y; a0.z += s0*wv.z; a0.w += s0*wv.w;
        a1.x += s1*wv.x; a1.y += s1*wv.y; a1.z += s1*wv.z; a1.w += s1*wv.w;
        a2.x += s2*wv.x; a2.y += s2*wv.y; a2.z += s2*wv.z; a2.w += s2*wv.w;
        a3.x += s3*wv.x; a3.y += s3*wv.y; a3.z += s3*wv.z; a3.w += s3*wv.w;
    }
    *(float4*)&part[((size_t)(s*4 + 0))*ND9 + n0] = a0;
    *(float4*)&part[((size_t)(s*4 + 1))*ND9 + n0] = a1;
    *(float4*)&part[((size_t)(s*4 + 2))*ND9 + n0] = a2;
    *(float4*)&part[((size_t)(s*4 + 3))*ND9 + n0] = a3;
}

// ---------------- ada stage 2 ----------------
__global__ void ada_reduce(const float* __restrict__ part, const float* __restrict__ ada_b,
                           float* __restrict__ mod) {
    int g = blockIdx.x * 1024 + threadIdx.x * 4;
    int r = g / ND9, n = g - r*ND9;
    float4 acc = *(const float4*)&ada_b[n];
    #pragma unroll
    for (int s = 0; s < 16; ++s) {
        float4 p = *(const float4*)&part[((size_t)(s*4 + r))*ND9 + n];
        acc.x += p.x; acc.y += p.y; acc.z += p.z; acc.w += p.w;
    }
    *(float4*)&mod[(size_t)r*ND9 + n] = acc;
}

// ---------------- resid(out) = copy(x), float4 ----------------
__global__ void cast_x4(const float* __restrict__ x, float* __restrict__ xc) {
    int i = (blockIdx.x * 256 + threadIdx.x) * 4;
    *(float4*)&xc[i] = *(const float4*)&x[i];
}

// ---------------- dst = src + bf16(gv), float4 ----------------
__global__ void resid_add(const float* __restrict__ src, const u16* __restrict__ gv,
                          float* __restrict__ dst) {
    int i = (blockIdx.x * 256 + threadIdx.x) * 4;
    float4 s = *(const float4*)&src[i];
    ushort4 g = *(const ushort4*)&gv[i];
    float4 o;
    o.x = s.x + bits2f(g.x); o.y = s.y + bits2f(g.y);
    o.z = s.z + bits2f(g.z); o.w = s.w + bits2f(g.w);
    *(float4*)&dst[i] = o;
}

// ---------------- fused: xn = src (+ gv); [dstf = xn]; y = mod(ln(xn)) ----------------
__global__ void resid_ln(const float* __restrict__ src, const u16* __restrict__ gv,
                         const float* __restrict__ mod, int jshift, int jscale,
                         float* __restrict__ dstf, bf16* __restrict__ y) {
    int row = blockIdx.x;
    int b = row / TT, t = row % TT;
    int cz = (t >= HALF) ? 1 : 0;
    const float* mp = mod + (size_t)(b*2 + cz) * ND9;
    int tid = threadIdx.x;
    int d0 = tid * 4;
    float4 s = *(const float4*)&src[(size_t)row*DD + d0];
    float v[4] = {s.x, s.y, s.z, s.w};
    if (gv) {
        ushort4 g = *(const ushort4*)&gv[(size_t)row*DD + d0];
        v[0] += bits2f(g.x); v[1] += bits2f(g.y); v[2] += bits2f(g.z); v[3] += bits2f(g.w);
    }
    if (dstf) *(float4*)&dstf[(size_t)row*DD + d0] = (float4){v[0], v[1], v[2], v[3]};
    float sum = v[0]+v[1]+v[2]+v[3];
    float ssq = v[0]*v[0]+v[1]*v[1]+v[2]*v[2]+v[3]*v[3];
    __shared__ float red[256];
    red[tid] = sum; __syncthreads();
    for (int o = 128; o > 0; o >>= 1) { if (tid < o) red[tid] += red[tid+o]; __syncthreads(); }
    float mean = red[0] * (1.f/DD);
    __syncthreads();
    red[tid] = ssq; __syncthreads();
    for (int o = 128; o > 0; o >>= 1) { if (tid < o) red[tid] += red[tid+o]; __syncthreads(); }
    float var = red[0] * (1.f/DD) - mean*mean;
    float rstd = rsqrtf(var + 1e-6f);
    float4 sh = *(const float4*)&mp[jshift*DD + d0];
    float4 sc = *(const float4*)&mp[jscale*DD + d0];
    ushort4 o4;
    o4.x = fb((v[0]-mean)*rstd*(1.f+sc.x) + sh.x);
    o4.y = fb((v[1]-mean)*rstd*(1.f+sc.y) + sh.y);
    o4.z = fb((v[2]-mean)*rstd*(1.f+sc.z) + sh.z);
    o4.w = fb((v[3]-mean)*rstd*(1.f+sc.w) + sh.w);
    *(ushort4*)((u16*)y + (size_t)row*DD + d0) = o4;
}

// ---------------- W (KxN f32) -> Wt (NxK bf16 bits) ----------------
__global__ void transpose_w(const float* __restrict__ W, u16* __restrict__ Wt, int K, int N) {
    __shared__ float T[32][33];
    int n0 = blockIdx.x * 32, k0 = blockIdx.y * 32;
    int lx = threadIdx.x & 31, ly = threadIdx.x >> 5;
    #pragma unroll
    for (int i = 0; i < 4; ++i)
        T[ly + i*8][lx] = W[(size_t)(k0 + ly + i*8)*N + n0 + lx];
    __syncthreads();
    #pragma unroll
    for (int i = 0; i < 4; ++i) {
        int n = ly + i*8;
        Wt[(size_t)(n0 + n)*K + k0 + lx] = fb(T[lx][n]);
    }
}

// ---------------- V slice of qkv -> vt[bh*16+head][d][key] ----------------
__global__ void vtrans(const u16* __restrict__ qkv, u16* __restrict__ vt) {
    __shared__ u16 T[64][72];
    int kt = blockIdx.y;
    int gh = blockIdx.x;
    int tid = threadIdx.x;
    int key = tid >> 2, c8 = (tid & 3) * 16;
    const u16* src = qkv + (size_t)((gh >> 4)*1024 + kt*64 + key)*3072 + 2048 + (gh & 15)*64 + c8;
    *(uint4*)&T[key][c8]     = *(const uint4*)src;
    *(uint4*)&T[key][c8 + 8] = *(const uint4*)(src + 8);
    __syncthreads();
    int d = tid >> 2, kc = (tid & 3) * 16;
    u16 tmp[16];
    #pragma unroll
    for (int i = 0; i < 16; ++i) tmp[i] = T[kc + i][d];
    u16* dst = vt + ((size_t)gh*64 + d)*1024 + kt*64 + kc;
    *(uint4*)&dst[0] = *(const uint4*)&tmp[0];
    *(uint4*)&dst[8] = *(const uint4*)&tmp[8];
}

// ---------------- epilogue helper ----------------
__device__ __forceinline__ void epi_store(u16* out, int o_off, int N, int mm, int n, float v,
                                          const float* mod, int jg, int epi) {
    if (epi == 0) {
        out[(size_t)(mm - o_off)*N + n] = fb(v);
    } else if (epi == 1) {
        float z = 0.7978845608028654f*(v + 0.044715f*v*v*v);
        out[(size_t)(mm - o_off)*N + n] = fb(v / (1.f + __expf(-2.f*z)));
    } else {
        int brow = mm / TT, tt2 = mm % TT;
        int cz = (tt2 >= HALF) ? 1 : 0;
        const float* mp = mod + (size_t)(brow*2 + cz)*ND9 + (size_t)jg*DD;
        out[(size_t)(mm - o_off)*N + n] = fb(mp[n]*v);
    }
}

// ---------------- MFMA GEMM 128x128 tile, BK=64, swizzled LDS ----------------
__global__ __launch_bounds__(256, 2) void gemm_mfma(
    const u16* __restrict__ A, const u16* __restrict__ Wt, const float* __restrict__ bias,
    u16* __restrict__ out, const float* __restrict__ mod, int jg,
    int m_base, int a_off, int o_off, int K, int N, int epi)
{
    __shared__ u16 As[128*64];
    __shared__ u16 Bs[128*64];
    int tid = threadIdx.x;
    int w = tid >> 6, lane = tid & 63;
    int quad = lane >> 4, l16 = lane & 15;
    int m0 = m_base + blockIdx.y * 128;
    int n0 = blockIdx.x * 128;
    int wr = (w & 1) * 64, wc = (w >> 1) * 64;

    f32x4 acc[4][4];
    #pragma unroll
    for (int i = 0; i < 4; ++i)
        #pragma unroll
        for (int j = 0; j < 4; ++j) acc[i][j] = (f32x4){0.f,0.f,0.f,0.f};

    const u16* Ag = A + (size_t)(m0 - a_off) * K;
    const u16* Bg = Wt + (size_t)n0 * K;
    int srow = lane >> 3;
    int scol = (((lane & 7) ^ ((lane >> 3) & 7))) * 8;
    int xsw = (l16 & 7);

    for (int k0 = 0; k0 < K; k0 += 64) {
        #pragma unroll
        for (int c = 0; c < 4; ++c) {
            int ch = w*4 + c;
            gl_lds16(Ag + (size_t)(ch*8 + srow)*K + k0 + scol, As + ch*512);
            gl_lds16(Bg + (size_t)(ch*8 + srow)*K + k0 + scol, Bs + ch*512);
        }
        __syncthreads();
        #pragma unroll
        for (int kk = 0; kk < 2; ++kk) {
            int pc = ((kk*4 + quad) ^ xsw) * 8;
            bf16x8 af[4], bfr[4];
            #pragma unroll
            for (int i = 0; i < 4; ++i) af[i] = *(const bf16x8*)&As[(wr + i*16 + l16)*64 + pc];
            #pragma unroll
            for (int j = 0; j < 4; ++j) bfr[j] = *(const bf16x8*)&Bs[(wc + j*16 + l16)*64 + pc];
            #pragma unroll
            for (int i = 0; i < 4; ++i)
                #pragma unroll
                for (int j = 0; j < 4; ++j)
                    acc[i][j] = __builtin_amdgcn_mfma_f32_16x16x32_bf16(af[i], bfr[j], acc[i][j], 0, 0, 0);
        }
        __syncthreads();
    }

    #pragma unroll
    for (int i = 0; i < 4; ++i)
        #pragma unroll
        for (int r = 0; r < 4; ++r) {
            int mm = m0 + wr + i*16 + quad*4 + r;
            #pragma unroll
            for (int j = 0; j < 4; ++j) {
                int n = n0 + wc + j*16 + l16;
                epi_store(out, o_off, N, mm, n, acc[i][j][r] + bias[n], mod, jg, epi);
            }
        }
}

// ---------------- MFMA GEMM 64x128 tile (narrow-N), BK=64, swizzled ----------------
__global__ __launch_bounds__(256, 2) void gemm64(
    const u16* __restrict__ A, const u16* __restrict__ Wt, const float* __restrict__ bias,
    u16* __restrict__ out, const float* __restrict__ mod, int jg,
    int m_base, int a_off, int o_off, int K, int N, int epi)
{
    __shared__ u16 As[64*64];
    __shared__ u16 Bs[128*64];
    int tid = threadIdx.x;
    int w = tid >> 6, lane = tid & 63;
    int quad = lane >> 4, l16 = lane & 15;
    int m0 = m_base + blockIdx.y * 64;
    int n0 = blockIdx.x * 128;

    f32x4 acc[4][2];
    #pragma unroll
    for (int i = 0; i < 4; ++i)
        #pragma unroll
        for (int j = 0; j < 2; ++j) acc[i][j] = (f32x4){0.f,0.f,0.f,0.f};

    const u16* Ag = A + (size_t)(m0 - a_off) * K;
    const u16* Bg = Wt + (size_t)n0 * K;
    int srow = lane >> 3;
    int scol = (((lane & 7) ^ ((lane >> 3) & 7))) * 8;
    int xsw = (l16 & 7);

    for (int k0 = 0; k0 < K; k0 += 64) {
        #pragma unroll
        for (int c = 0; c < 2; ++c) {
            int ch = w*2 + c;
            gl_lds16(Ag + (size_t)(ch*8 + srow)*K + k0 + scol, As + ch*512);
        }
        #pragma unroll
        for (int c = 0; c < 4; ++c) {
            int ch = w*4 + c;
            gl_lds16(Bg + (size_t)(ch*8 + srow)*K + k0 + scol, Bs + ch*512);
        }
        __syncthreads();
        #pragma unroll
        for (int kk = 0; kk < 2; ++kk) {
            int pc = ((kk*4 + quad) ^ xsw) * 8;
            bf16x8 af[4], bfr[2];
            #pragma unroll
            for (int i = 0; i < 4; ++i) af[i] = *(const bf16x8*)&As[(i*16 + l16)*64 + pc];
            #pragma unroll
            for (int j = 0; j < 2; ++j) bfr[j] = *(const bf16x8*)&Bs[(w*32 + j*16 + l16)*64 + pc];
            #pragma unroll
            for (int i = 0; i < 4; ++i)
                #pragma unroll
                for (int j = 0; j < 2; ++j)
                    acc[i][j] = __builtin_amdgcn_mfma_f32_16x16x32_bf16(af[i], bfr[j], acc[i][j], 0, 0, 0);
        }
        __syncthreads();
    }

    #pragma unroll
    for (int i = 0; i < 4; ++i)
        #pragma unroll
        for (int r = 0; r < 4; ++r) {
            int mm = m0 + i*16 + quad*4 + r;
            #pragma unroll
            for (int j = 0; j < 2; ++j) {
                int n = n0 + w*32 + j*16 + l16;
                epi_store(out, o_off, N, mm, n, acc[i][j][r] + bias[n], mod, jg, epi);
            }
        }
}

// ---------------- MFMA flash attention (S^T trick + reg-prefetch pipeline) ----------------
// grid (NH, 16 qtiles, 4 bh) — head fastest for XCD L2 locality of K/V re-reads.
// S^T = K·Q^T puts q on lanes (col=l16), keys on regs/quads: softmax = in-reg reduce + 2 shfl.
__global__ __launch_bounds__(256) void attn_mfma(const u16* __restrict__ qkv,
                                                 const u16* __restrict__ vt,
                                                 u16* __restrict__ attn_out, int kv_swap) {
    __shared__ u16 Ks[64][72];       // [key][d]
    __shared__ u16 Vs[64][72];       // [d][key]
    __shared__ u16 Ps[4][16][72];    // per-wave P: [q=l16][key]
    int head = blockIdx.x, qt = blockIdx.y, bh = blockIdx.z;
    int kvbh = kv_swap ? (bh ^ 1) : bh;
    int tid = threadIdx.x;
    int w = tid >> 6, lane = tid & 63;
    int quad = lane >> 4, l16 = lane & 15;
    int qrow0 = bh*1024 + qt*64 + w*16;

    const u16* qp = qkv + (size_t)(qrow0 + l16)*3072 + head*64;
    bf16x8 qa0 = *(const bf16x8*)(qp + quad*8);        // Q[q=l16][d=quad*8+j]
    bf16x8 qa1 = *(const bf16x8*)(qp + 32 + quad*8);

    f32x4 oacc[4];
    #pragma unroll
    for (int i = 0; i < 4; ++i) oacc[i] = (f32x4){0.f,0.f,0.f,0.f};
    float mst = -3e38f, lst = 0.f;                     // per-q (lane) online-softmax state

    int skey = tid >> 2, sc8 = (tid & 3) * 16;
    const u16* kbase = qkv + (size_t)(kvbh*1024 + skey)*3072 + 1024 + head*64 + sc8;
    const u16* vbase = vt + ((size_t)(kvbh*16 + head)*64 + skey)*1024 + sc8;

    uint4 kr0 = *(const uint4*)kbase;
    uint4 kr1 = *(const uint4*)(kbase + 8);
    uint4 vr0 = *(const uint4*)vbase;
    uint4 vr1 = *(const uint4*)(vbase + 8);

    for (int kt = 0; kt < 16; ++kt) {
        __syncthreads();
        *(uint4*)&Ks[skey][sc8]     = kr0;
        *(uint4*)&Ks[skey][sc8 + 8] = kr1;
        *(uint4*)&Vs[skey][sc8]     = vr0;
        *(uint4*)&Vs[skey][sc8 + 8] = vr1;
        __syncthreads();
        if (kt < 15) {                                  // prefetch next tile into regs
            const u16* kp = kbase + (size_t)(kt + 1)*64*3072;
            kr0 = *(const uint4*)kp;
            kr1 = *(const uint4*)(kp + 8);
            const u16* vp = vbase + (kt + 1)*64;
            vr0 = *(const uint4*)vp;
            vr1 = *(const uint4*)(vp + 8);
        }

        // S^T[key][q] = K·Q^T : first operand rows = keys, second cols = q
        f32x4 sacc[4];
        #pragma unroll
        for (int nt = 0; nt < 4; ++nt) sacc[nt] = (f32x4){0.f,0.f,0.f,0.f};
        #pragma unroll
        for (int nt = 0; nt < 4; ++nt) {
            bf16x8 kb0 = *(const bf16x8*)&Ks[nt*16 + l16][quad*8];
            bf16x8 kb1 = *(const bf16x8*)&Ks[nt*16 + l16][32 + quad*8];
            sacc[nt] = __builtin_amdgcn_mfma_f32_16x16x32_bf16(kb0, qa0, sacc[nt], 0, 0, 0);
            sacc[nt] = __builtin_amdgcn_mfma_f32_16x16x32_bf16(kb1, qa1, sacc[nt], 0, 0, 0);
        }

        // softmax over keys (16 in-lane + 4 quads) per q=l16
        float sv[4][4];
        float tm = -3e38f;
        #pragma unroll
        for (int nt = 0; nt < 4; ++nt)
            #pragma unroll
            for (int r = 0; r < 4; ++r) {
                sv[nt][r] = sacc[nt][r] * 0.125f;
                tm = fmaxf(tm, sv[nt][r]);
            }
        tm = fmaxf(tm, __shfl_xor(tm, 16));
        tm = fmaxf(tm, __shfl_xor(tm, 32));
        float mnew = fmaxf(mst, tm);
        float alpha = __expf(mst - mnew);
        float ls = 0.f;
        #pragma unroll
        for (int nt = 0; nt < 4; ++nt) {
            float p0 = __expf(sv[nt][0] - mnew), p1 = __expf(sv[nt][1] - mnew);
            float p2 = __expf(sv[nt][2] - mnew), p3 = __expf(sv[nt][3] - mnew);
            ls += (p0 + p1) + (p2 + p3);
            ushort4 pk = {fb(p0), fb(p1), fb(p2), fb(p3)};
            *(ushort4*)&Ps[w][l16][nt*16 + quad*4] = pk;
        }
        ls += __shfl_xor(ls, 16);
        ls += __shfl_xor(ls, 32);
        lst = lst*alpha + ls;
        mst = mnew;
        #pragma unroll
        for (int dt = 0; dt < 4; ++dt)
            #pragma unroll
            for (int r = 0; r < 4; ++r) oacc[dt][r] *= alpha;

        // O^T[d][q] += V^T·P^T : first operand rows = d, second cols = q
        bf16x8 pa0 = *(const bf16x8*)&Ps[w][l16][quad*8];
        bf16x8 pa1 = *(const bf16x8*)&Ps[w][l16][32 + quad*8];
        #pragma unroll
        for (int dt = 0; dt < 4; ++dt) {
            bf16x8 vb0 = *(const bf16x8*)&Vs[dt*16 + l16][quad*8];
            bf16x8 vb1 = *(const bf16x8*)&Vs[dt*16 + l16][32 + quad*8];
            oacc[dt] = __builtin_amdgcn_mfma_f32_16x16x32_bf16(vb0, pa0, oacc[dt], 0, 0, 0);
            oacc[dt] = __builtin_amdgcn_mfma_f32_16x16x32_bf16(vb1, pa1, oacc[dt], 0, 0, 0);
        }
    }
    float rl = 1.f / lst;
    #pragma unroll
    for (int dt = 0; dt < 4; ++dt) {
        ushort4 o4 = {fb(oacc[dt][0]*rl), fb(oacc[dt][1]*rl), fb(oacc[dt][2]*rl), fb(oacc[dt][3]*rl)};
        *(ushort4*)&attn_out[(size_t)(qrow0 + l16)*DD + head*64 + dt*16 + quad*4] = o4;
    }
}

extern "C" void kernel_launch(void* const* d_in, const int* in_sizes, int n_in,
                              void* d_out, int out_size, void* d_ws, size_t ws_size,
                              hipStream_t stream) {
    const float* x          = (const float*)d_in[0];
    const float* c          = (const float*)d_in[1];
    const float* attn_qkv_w = (const float*)d_in[2];
    const float* attn_qkv_b = (const float*)d_in[3];
    const float* attn_proj_w= (const float*)d_in[4];
    const float* attn_proj_b= (const float*)d_in[5];
    const float* crs_qkv_w  = (const float*)d_in[6];
    const float* crs_qkv_b  = (const float*)d_in[7];
    const float* crs_proj_w = (const float*)d_in[8];
    const float* crs_proj_b = (const float*)d_in[9];
    const float* fc1_w      = (const float*)d_in[10];
    const float* fc1_b      = (const float*)d_in[11];
    const float* fc2_w      = (const float*)d_in[12];
    const float* fc2_b      = (const float*)d_in[13];
    const float* ada_w      = (const float*)d_in[14];
    const float* ada_b      = (const float*)d_in[15];
    float* out = (float*)d_out;     // f32 running residual (= x; MSA branch excluded per reference)

    // ws: mod 0.25 MB | R1 16 MB | Yr 8 MB | AOr 8 MB | BIGr 24 MB = 56.25 MB
    char* ws = (char*)d_ws;
    float* mod = (float*)ws;
    char* R1   = ws + (256u<<10);
    char* Yr   = R1 + (16u<<20);
    char* AOr  = Yr + (8u<<20);
    char* BIGr = AOr + (8u<<20);

    u16*   wt_a  = (u16*)R1;                   // 6 MB qkv weight T
    u16*   vt    = (u16*)(R1 + (8u<<20));      // 8 MB V-transpose
    bf16*  y     = (bf16*)Yr;                  // 8 MB ln output
    u16*   wt_p  = (u16*)Yr;                   // 2 MB proj weight T (y dead)
    u16*   attn_o= (u16*)AOr;                  // 8 MB
    u16*   big   = (u16*)BIGr;                 // 24 MB qkv
    u16*   gvB   = (u16*)BIGr;                 // 8 MB gated branch output (big dead)
    u16*   gvY   = (u16*)Yr;                   // 8 MB gated fc2 output (y dead)
    u16*   hstage= (u16*)AOr;                  // 32 MB fc1 out (AOr+BIGr contiguous)
    u16*   fc1_t = (u16*)R1;                   // 8 MB
    u16*   fc2_t = (u16*)(R1 + (8u<<20));      // 8 MB
    float* apart = (float*)BIGr;               // 2.4 MB ada partials (pre-MSA only)

    ada_part<<<dim3(9, 16), 256, 0, stream>>>(c, ada_w, apart);
    ada_reduce<<<36, 256, 0, stream>>>(apart, ada_b, mod);
    cast_x4<<<4096, 256, 0, stream>>>(x, out);

    // ================= MSA =================
    transpose_w<<<dim3(3*DD/32, DD/32), 256, 0, stream>>>(attn_qkv_w, wt_a, DD, 3*DD);
    resid_ln<<<ROWS, 256, 0, stream>>>(out, nullptr, mod, 0, 1, nullptr, y);
    gemm_mfma<<<dim3(3*DD/128, ROWS/128), 256, 0, stream>>>((const u16*)y, wt_a, attn_qkv_b,
                                                            big, nullptr, 0, 0, 0, 0, DD, 3*DD, 0);
    vtrans<<<dim3(64, 16), 256, 0, stream>>>(big, vt);
    attn_mfma<<<dim3(NH, 16, 4), 256, 0, stream>>>(big, vt, attn_o, 0);
    transpose_w<<<dim3(DD/32, DD/32), 256, 0, stream>>>(attn_proj_w, wt_p, DD, DD);
    gemm64<<<dim3(DD/128, ROWS/64), 256, 0, stream>>>(attn_o, wt_p, attn_proj_b,
                                                      gvB, mod, 2, 0, 0, 0, DD, DD, 3);
    // y = mod(ln(out + gvB)) for MCA; running residual (out) unchanged per reference
    resid_ln<<<ROWS, 256, 0, stream>>>(out, gvB, mod, 3, 4, nullptr, y);

    // ================= MCA =================
    transpose_w<<<dim3(3*DD/32, DD/32), 256, 0, stream>>>(crs_qkv_w, wt_a, DD, 3*DD);
    gemm_mfma<<<dim3(3*DD/128, ROWS/128), 256, 0, stream>>>((const u16*)y, wt_a, crs_qkv_b,
                                                            big, nullptr, 0, 0, 0, 0, DD, 3*DD, 0);
    vtrans<<<dim3(64, 16), 256, 0, stream>>>(big, vt);
    attn_mfma<<<dim3(NH, 16, 4), 256, 0, stream>>>(big, vt, attn_o, 1);
    transpose_w<<<dim3(DD/32, DD/32), 256, 0, stream>>>(crs_proj_w, wt_p, DD, DD);
    gemm64<<<dim3(DD/128, ROWS/64), 256, 0, stream>>>(attn_o, wt_p, crs_proj_b,
                                                      gvB, mod, 5, 0, 0, 0, DD, DD, 3);
    // out += gvB (store), y = mod(ln(out)) for MLP
    resid_ln<<<ROWS, 256, 0, stream>>>(out, gvB, mod, 6, 7, out, y);

    // ================= MLP =================
    transpose_w<<<dim3(DHID/32, DD/32), 256, 0, stream>>>(fc1_w, fc1_t, DD, DHID);
    transpose_w<<<dim3(DD/32, DHID/32), 256, 0, stream>>>(fc2_w, fc2_t, DHID, DD);
    gemm_mfma<<<dim3(DHID/128, ROWS/128), 256, 0, stream>>>((const u16*)y, fc1_t, fc1_b,
                                                            hstage, nullptr, 0, 0, 0, 0, DD, DHID, 1);
    gemm64<<<dim3(DD/128, ROWS/64), 256, 0, stream>>>(hstage, fc2_t, fc2_b,
                                                      gvY, mod, 8, 0, 0, 0, DHID, DD, 3);
    resid_add<<<4096, 256, 0, stream>>>(out, gvY, out);
}